// Round 1
// baseline (1390.493 us; speedup 1.0000x reference)
//
#include <hip/hip_runtime.h>

typedef unsigned short u16;
typedef unsigned int   u32;

using bf16x8 = __attribute__((ext_vector_type(8))) short;
using f32x4  = __attribute__((ext_vector_type(4))) float;

#define SEQ    2048
#define DIMC   2048
#define TOK    4096
#define QKV_N  3072
#define GU_N   11008
#define MLP_P  5504
#define MLP_R  5461
#define ATT_SCALE 0.08838834764831845f

struct alignas(8) U16x4 { u16 x, y, z, w; };

__device__ __forceinline__ float bf2f(u16 v){ return __uint_as_float(((u32)v) << 16); }
__device__ __forceinline__ u16 f2bf(float f){
  u32 x = __float_as_uint(f);
  u32 r = (x + 0x7fffu + ((x >> 16) & 1u)) >> 16;
  return (u16)r;
}

__device__ __forceinline__ float waveRedSum(float v){
#pragma unroll
  for (int o = 32; o > 0; o >>= 1) v += __shfl_xor(v, o);
  return v;
}
__device__ __forceinline__ float waveRedMax(float v){
#pragma unroll
  for (int o = 32; o > 0; o >>= 1) v = fmaxf(v, __shfl_xor(v, o));
  return v;
}

// async global->LDS, 16B per lane. LDS layout must be base + lane*16.
#define GLD16(gp, lp) __builtin_amdgcn_global_load_lds( \
    (__attribute__((address_space(1))) void*)(gp), \
    (__attribute__((address_space(3))) void*)(lp), 16, 0, 0)

// ---------------- weight scale: sum |w| ----------------
__global__ __launch_bounds__(256) void k_abssum(const float4* __restrict__ w, int n4,
                                                float* __restrict__ slot){
  float s = 0.f;
  for (int i = blockIdx.x*256 + threadIdx.x; i < n4; i += gridDim.x*256){
    float4 v = w[i];
    s += fabsf(v.x) + fabsf(v.y) + fabsf(v.z) + fabsf(v.w);
  }
  s = waveRedSum(s);
  __shared__ float sm[4];
  int lane = threadIdx.x & 63, wv = threadIdx.x >> 6;
  if (lane == 0) sm[wv] = s;
  __syncthreads();
  if (threadIdx.x == 0) atomicAdd(slot, sm[0]+sm[1]+sm[2]+sm[3]);
}

// sums at sc[0..6] -> deq (=clip(mean,1e-5)) at sc[8..14]
__global__ void k_finalize(float* __restrict__ sc){
  if (threadIdx.x == 0){
    const float counts[7] = {4194304.f, 1048576.f, 1048576.f, 4194304.f,
                             11184128.f, 11184128.f, 11184128.f};
    for (int i = 0; i < 7; i++) sc[8+i] = fmaxf(sc[i]/counts[i], 1e-5f);
  }
}

// ---------------- ternary weight quant -> bf16 {-1,0,1} ----------------
__global__ __launch_bounds__(256) void k_wquant(const float4* __restrict__ src,
                                                U16x4* __restrict__ dst, int n4,
                                                const float* __restrict__ deqp){
  float ws = 1.0f / deqp[0];
  for (int i = blockIdx.x*256 + threadIdx.x; i < n4; i += gridDim.x*256){
    float4 v = src[i];
    U16x4 o;
    o.x = f2bf(fminf(fmaxf(rintf(v.x*ws), -1.f), 1.f));
    o.y = f2bf(fminf(fmaxf(rintf(v.y*ws), -1.f), 1.f));
    o.z = f2bf(fminf(fmaxf(rintf(v.z*ws), -1.f), 1.f));
    o.w = f2bf(fminf(fmaxf(rintf(v.w*ws), -1.f), 1.f));
    dst[i] = o;
  }
}

// down_w [2048][5461] -> [2048][5504] padded with zeros
__global__ __launch_bounds__(256) void k_wquant_down(const float* __restrict__ src,
                                                     u16* __restrict__ dst,
                                                     const float* __restrict__ deqp){
  int i = blockIdx.x*256 + threadIdx.x;
  const int total = 2048*MLP_P;
  if (i >= total) return;
  float ws = 1.0f / deqp[0];
  int r = i / MLP_P;
  int c = i - r*MLP_P;
  float t = 0.f;
  if (c < MLP_R) t = fminf(fmaxf(rintf(src[(long)r*MLP_R + c]*ws), -1.f), 1.f);
  dst[i] = f2bf(t);
}

// ---------------- rmsnorm (optional) + act_quant over 2048 ----------------
__global__ __launch_bounds__(256) void k_rmsq(const float* __restrict__ in,
                                              const float* __restrict__ nw,
                                              u16* __restrict__ outq,
                                              float* __restrict__ rowdeq, int do_norm){
  const int row = blockIdx.x, tid = threadIdx.x;
  const float* xp = in + (long)row * DIMC;
  float v[8];
  float ss = 0.f;
#pragma unroll
  for (int j = 0; j < 8; j++){ v[j] = xp[j*256 + tid]; ss += v[j]*v[j]; }
  __shared__ float sm[8];
  int lane = tid & 63, wv = tid >> 6;
  ss = waveRedSum(ss);
  if (lane == 0) sm[wv] = ss;
  __syncthreads();
  float rms = 1.f;
  if (do_norm){
    float tot = sm[0]+sm[1]+sm[2]+sm[3];
    rms = rsqrtf(tot * (1.0f/DIMC) + 1.1920929e-07f);
  }
  float h[8];
  float amax = 0.f;
#pragma unroll
  for (int j = 0; j < 8; j++){
    float hv = v[j];
    if (do_norm) hv = hv * rms * nw[j*256 + tid];
    h[j] = hv;
    amax = fmaxf(amax, fabsf(hv));
  }
  amax = waveRedMax(amax);
  if (lane == 0) sm[4+wv] = amax;
  __syncthreads();
  float gmax = fmaxf(fmaxf(sm[4],sm[5]), fmaxf(sm[6],sm[7]));
  float sc = 127.0f / fmaxf(gmax, 1e-5f);
#pragma unroll
  for (int j = 0; j < 8; j++){
    float q = fminf(fmaxf(rintf(h[j]*sc), -128.f), 127.f);
    outq[(long)row*DIMC + j*256 + tid] = f2bf(q);
  }
  if (tid == 0) rowdeq[row] = 1.0f / sc;
}

// ---------------- RoPE in place on cols [0,2560) of y_qkv ----------------
__global__ __launch_bounds__(256) void k_rope(u16* __restrict__ y, const int* __restrict__ pos_ids){
  int idx = blockIdx.x*256 + threadIdx.x;     // < 4096*1280
  int m = idx / 1280;
  int p = idx - m*1280;
  int c = p*2;
  int i = (c & 127) >> 1;
  float pos = (float)pos_ids[m];
  float inv = expf((float)i * -0.14391156831212787f);  // 10000^(-i/64)
  float f = pos * inv;
  float sn, cs;
  sincosf(f, &sn, &cs);
  u32* pr = (u32*)(y + (long)m*QKV_N + c);
  u32 both = *pr;
  float x0 = bf2f((u16)(both & 0xffffu));
  float x1 = bf2f((u16)(both >> 16));
  u16 o0 = f2bf(x0*cs - x1*sn);
  u16 o1 = f2bf(x1*cs + x0*sn);
  *pr = (u32)o0 | ((u32)o1 << 16);
}

// ---------------- GEMM: y = A(bf16-int rows) @ B(bf16-ternary rows)^T ----------------
// MODE 0: QKV  -> bf16 out + bias, deq by section {q,k,v}, ldc=3072
// MODE 1: fp32 out = acc*rd*deq + resid, ldc=N       (O-proj and Down)
// MODE 2: GU   -> bf16 out, deq by half {gate,up}, ldc=11008
template<int MODE>
__global__ __launch_bounds__(256) void k_gemm(
    const u16* __restrict__ A, const u16* __restrict__ B,
    int K, int lda, int ldb, int ldc,
    const float* __restrict__ rowdeq, const float* __restrict__ deqp,
    const float* __restrict__ bq, const float* __restrict__ bk, const float* __restrict__ bv,
    const float* __restrict__ resid, float* __restrict__ outF, u16* __restrict__ outB)
{
  __shared__ u16 sA[128*32];
  __shared__ u16 sB[128*32];
  const int tid = threadIdx.x;
  const int lane = tid & 63, wv = tid >> 6;
  const int wr = wv >> 1, wc = wv & 1;
  const long m0 = (long)blockIdx.y * 128;
  const long n0 = (long)blockIdx.x * 128;
  const int r = lane & 15, qq = lane >> 4;

  f32x4 acc[4][4];
#pragma unroll
  for (int i = 0; i < 4; i++)
#pragma unroll
    for (int j = 0; j < 4; j++) acc[i][j] = (f32x4){0.f,0.f,0.f,0.f};

  const int c0 = tid, c1 = tid + 256;
  const u16* gA0 = A + (m0 + (c0>>2))*lda + (c0&3)*8;
  const u16* gA1 = A + (m0 + (c1>>2))*lda + (c1&3)*8;
  const u16* gB0 = B + (n0 + (c0>>2))*ldb + (c0&3)*8;
  const u16* gB1 = B + (n0 + (c1>>2))*ldb + (c1&3)*8;
  u16* lA0 = sA + c0*8; u16* lA1 = sA + c1*8;
  u16* lB0 = sB + c0*8; u16* lB1 = sB + c1*8;

  for (int kt = 0; kt < K; kt += 32){
    __syncthreads();
    GLD16(gA0 + kt, lA0);
    GLD16(gA1 + kt, lA1);
    GLD16(gB0 + kt, lB0);
    GLD16(gB1 + kt, lB1);
    __syncthreads();
    bf16x8 aF[4], bF[4];
#pragma unroll
    for (int i = 0; i < 4; i++) aF[i] = *(const bf16x8*)(sA + (wr*64 + 16*i + r)*32 + qq*8);
#pragma unroll
    for (int j = 0; j < 4; j++) bF[j] = *(const bf16x8*)(sB + (wc*64 + 16*j + r)*32 + qq*8);
#pragma unroll
    for (int i = 0; i < 4; i++)
#pragma unroll
      for (int j = 0; j < 4; j++)
        acc[i][j] = __builtin_amdgcn_mfma_f32_16x16x32_bf16(aF[i], bF[j], acc[i][j], 0, 0, 0);
  }

#pragma unroll
  for (int i = 0; i < 4; i++){
#pragma unroll
    for (int t = 0; t < 4; t++){
      const long row = m0 + wr*64 + 16*i + 4*qq + t;
      const float rdv = rowdeq[row];
#pragma unroll
      for (int j = 0; j < 4; j++){
        const long col = n0 + wc*64 + 16*j + r;
        float vv = acc[i][j][t];
        if (MODE == 0){
          int sec = (col >= 2048) + (col >= 2560);
          float dq = deqp[sec];
          float bias = (sec == 0) ? bq[col] : (sec == 1) ? bk[col-2048] : bv[col-2560];
          outB[row*(long)ldc + col] = f2bf(vv*rdv*dq + bias);
        } else if (MODE == 1){
          outF[row*(long)ldc + col] = vv*rdv*deqp[0] + resid[row*(long)ldc + col];
        } else {
          int sec = (col >= 5504) ? 1 : 0;
          outB[row*(long)ldc + col] = f2bf(vv*rdv*deqp[sec]);
        }
      }
    }
  }
}

// ---------------- flash attention (bf16 MFMA, online softmax) ----------------
__global__ __launch_bounds__(256) void k_attn(const u16* __restrict__ Y, float* __restrict__ O)
{
  __shared__ u16 Qs[64][136];
  __shared__ u16 Ks[64][136];
  __shared__ u16 Vt[128][72];
  __shared__ u16 Ps[64][72];

  const int qt = blockIdx.x;           // q tile 0..31
  const int bh = blockIdx.y;           // 0..31
  const int b = bh >> 4, h = bh & 15, hk = h >> 2;
  const int q0 = qt * 64;
  const int tid = threadIdx.x;
  const int lane = tid & 63, wv = tid >> 6;
  const int r = lane & 15, qq = lane >> 4;
  const long rowbase = (long)b * SEQ;

  for (int c = tid; c < 1024; c += 256){
    int rw = c >> 4, c8 = c & 15;
    const int4 val = *(const int4*)(Y + (rowbase + q0 + rw)*QKV_N + h*128 + c8*8);
    *(int4*)&Qs[rw][c8*8] = val;
  }
  __syncthreads();
  bf16x8 qf[4];
#pragma unroll
  for (int kc = 0; kc < 4; kc++) qf[kc] = *(const bf16x8*)&Qs[wv*16 + r][kc*32 + qq*8];

  f32x4 accO[8];
#pragma unroll
  for (int jn = 0; jn < 8; jn++) accO[jn] = (f32x4){0.f,0.f,0.f,0.f};
  float m_run[4] = {-INFINITY,-INFINITY,-INFINITY,-INFINITY};
  float l_run[4] = {0.f,0.f,0.f,0.f};

  for (int kt = 0; kt <= qt; kt++){
    __syncthreads();
    for (int c = tid; c < 1024; c += 256){
      int rw = c >> 4, c8 = c & 15;
      const int4 kvv = *(const int4*)(Y + (rowbase + kt*64 + rw)*QKV_N + 2048 + hk*128 + c8*8);
      *(int4*)&Ks[rw][c8*8] = kvv;
      int4 vv = *(const int4*)(Y + (rowbase + kt*64 + rw)*QKV_N + 2560 + hk*128 + c8*8);
      const u16* vp = (const u16*)&vv;
#pragma unroll
      for (int e = 0; e < 8; e++) Vt[c8*8 + e][rw] = vp[e];
    }
    __syncthreads();

    float sv[4][4];
#pragma unroll
    for (int j = 0; j < 4; j++){
      f32x4 a = (f32x4){0.f,0.f,0.f,0.f};
#pragma unroll
      for (int kc = 0; kc < 4; kc++){
        bf16x8 kf = *(const bf16x8*)&Ks[16*j + r][kc*32 + qq*8];
        a = __builtin_amdgcn_mfma_f32_16x16x32_bf16(qf[kc], kf, a, 0, 0, 0);
      }
#pragma unroll
      for (int t = 0; t < 4; t++) sv[j][t] = a[t] * ATT_SCALE;
    }
    if (kt == qt){
#pragma unroll
      for (int j = 0; j < 4; j++){
        int key = kt*64 + 16*j + r;
#pragma unroll
        for (int t = 0; t < 4; t++){
          int qr = q0 + wv*16 + 4*qq + t;
          if (key > qr) sv[j][t] = -INFINITY;
        }
      }
    }
#pragma unroll
    for (int t = 0; t < 4; t++){
      float mm = fmaxf(fmaxf(sv[0][t],sv[1][t]), fmaxf(sv[2][t],sv[3][t]));
#pragma unroll
      for (int o = 8; o > 0; o >>= 1) mm = fmaxf(mm, __shfl_xor(mm, o));
      float mnew = fmaxf(m_run[t], mm);
      float alpha = expf(m_run[t] - mnew);
      m_run[t] = mnew;
      float ps = 0.f;
#pragma unroll
      for (int j = 0; j < 4; j++){
        float p = expf(sv[j][t] - mnew);
        ps += p;
        Ps[wv*16 + 4*qq + t][16*j + r] = f2bf(p);
      }
#pragma unroll
      for (int o = 8; o > 0; o >>= 1) ps += __shfl_xor(ps, o);
      l_run[t] = l_run[t]*alpha + ps;
#pragma unroll
      for (int jn = 0; jn < 8; jn++) accO[jn][t] *= alpha;
    }
#pragma unroll
    for (int kc = 0; kc < 2; kc++){
      bf16x8 pf = *(const bf16x8*)&Ps[wv*16 + r][kc*32 + qq*8];
#pragma unroll
      for (int jn = 0; jn < 8; jn++){
        bf16x8 vf = *(const bf16x8*)&Vt[16*jn + r][kc*32 + qq*8];
        accO[jn] = __builtin_amdgcn_mfma_f32_16x16x32_bf16(pf, vf, accO[jn], 0, 0, 0);
      }
    }
  }
  float inv[4];
#pragma unroll
  for (int t = 0; t < 4; t++) inv[t] = 1.0f / l_run[t];
#pragma unroll
  for (int jn = 0; jn < 8; jn++){
#pragma unroll
    for (int t = 0; t < 4; t++){
      long row = rowbase + q0 + wv*16 + 4*qq + t;
      O[row*DIMC + h*128 + 16*jn + r] = accO[jn][t]*inv[t];
    }
  }
}

// ---------------- SwiGLU + act_quant in place over y_gu rows ----------------
__global__ __launch_bounds__(256) void k_swiglu(u16* __restrict__ ygu, float* __restrict__ rowdeq){
  const int row = blockIdx.x, tid = threadIdx.x;
  u16* base = ygu + (long)row * GU_N;
  float h[22];
  float amax = 0.f;
#pragma unroll
  for (int it = 0; it < 22; it++){
    int j = it*256 + tid;
    float hv = 0.f;
    if (j < MLP_P){
      float g = bf2f(base[j]);
      float u = bf2f(base[MLP_P + j]);
      hv = g * (1.0f/(1.0f + expf(-g))) * u;
    }
    h[it] = hv;
    amax = fmaxf(amax, fabsf(hv));
  }
  amax = waveRedMax(amax);
  __shared__ float sm[4];
  int lane = tid & 63, wv = tid >> 6;
  if (lane == 0) sm[wv] = amax;
  __syncthreads();
  float gmax = fmaxf(fmaxf(sm[0],sm[1]), fmaxf(sm[2],sm[3]));
  float sc = 127.0f / fmaxf(gmax, 1e-5f);
#pragma unroll
  for (int it = 0; it < 22; it++){
    int j = it*256 + tid;
    if (j < MLP_P){
      float q = fminf(fmaxf(rintf(h[it]*sc), -128.f), 127.f);
      base[j] = f2bf(q);
    }
  }
  if (tid == 0) rowdeq[row] = 1.0f/sc;
}

extern "C" void kernel_launch(void* const* d_in, const int* in_sizes, int n_in,
                              void* d_out, int out_size, void* d_ws, size_t ws_size,
                              hipStream_t stream)
{
  (void)in_sizes; (void)n_in; (void)out_size; (void)ws_size;
  const float* x   = (const float*)d_in[0];
  const int*   pos = (const int*)d_in[1];
  const float* n1w = (const float*)d_in[2];
  const float* qw  = (const float*)d_in[3];
  const float* qb  = (const float*)d_in[4];
  const float* kw  = (const float*)d_in[5];
  const float* kb  = (const float*)d_in[6];
  const float* vw  = (const float*)d_in[7];
  const float* vb  = (const float*)d_in[8];
  const float* ow  = (const float*)d_in[9];
  const float* n2w = (const float*)d_in[10];
  const float* gw  = (const float*)d_in[11];
  const float* uw  = (const float*)d_in[12];
  const float* dw  = (const float*)d_in[13];
  float* out = (float*)d_out;
  char* ws = (char*)d_ws;

  // workspace layout (total needed ~195.6 MB, all 256B aligned)
  float* sc   = (float*)ws;                 // [0..6] sums, [8..14] deq
  u16* Wqkv   = (u16*)(ws + 256);           // [3072][2048] bf16
  u16* Wo     = (u16*)(ws + 12583168);      // [2048][2048]
  u16* Wgu    = (u16*)(ws + 20971776);      // [11008][2048] (rows 5461..5503 & 10965..11007 zero)
  u16* Wd     = (u16*)(ws + 66060544);      // [2048][5504]
  u16* actq   = (u16*)(ws + 88604928);      // [4096][2048] bf16 (reused h1/outq/h2)
  float* rd   = (float*)(ws + 105382144);   // [4096] row deq (reused)
  char* xreg  = ws + 105398528;             // big overlay region (90.2 MB)
  u16* yqkv   = (u16*)xreg;                 // [4096][3072] bf16
  float* attn = (float*)(xreg + 25165824);  // [4096][2048] fp32
  u16* ygu    = (u16*)xreg;                 // [4096][11008] bf16 (after attention phase)

  // ---- weight scales + ternary quant ----
  hipMemsetAsync(sc, 0, 64, stream);
  k_abssum<<<512,256,0,stream>>>((const float4*)qw, 4194304/4, sc+0);
  k_abssum<<<512,256,0,stream>>>((const float4*)kw, 1048576/4, sc+1);
  k_abssum<<<512,256,0,stream>>>((const float4*)vw, 1048576/4, sc+2);
  k_abssum<<<512,256,0,stream>>>((const float4*)ow, 4194304/4, sc+3);
  k_abssum<<<512,256,0,stream>>>((const float4*)gw, 11184128/4, sc+4);
  k_abssum<<<512,256,0,stream>>>((const float4*)uw, 11184128/4, sc+5);
  k_abssum<<<512,256,0,stream>>>((const float4*)dw, 11184128/4, sc+6);
  k_finalize<<<1,64,0,stream>>>(sc);
  k_wquant<<<1024,256,0,stream>>>((const float4*)qw, (U16x4*)Wqkv,               4194304/4,  sc+8);
  k_wquant<<<1024,256,0,stream>>>((const float4*)kw, (U16x4*)(Wqkv + 2048l*2048), 1048576/4, sc+9);
  k_wquant<<<1024,256,0,stream>>>((const float4*)vw, (U16x4*)(Wqkv + 2560l*2048), 1048576/4, sc+10);
  k_wquant<<<1024,256,0,stream>>>((const float4*)ow, (U16x4*)Wo,                 4194304/4,  sc+11);
  k_wquant<<<1024,256,0,stream>>>((const float4*)gw, (U16x4*)Wgu,                11184128/4, sc+12);
  k_wquant<<<1024,256,0,stream>>>((const float4*)uw, (U16x4*)(Wgu + 5504l*2048), 11184128/4, sc+13);
  hipMemsetAsync(Wgu + 5461l*2048,        0, 43l*2048*2, stream);
  hipMemsetAsync(Wgu + (5504l+5461)*2048, 0, 43l*2048*2, stream);
  k_wquant_down<<<44032,256,0,stream>>>(dw, Wd, sc+14);

  // ---- attention half ----
  k_rmsq<<<4096,256,0,stream>>>(x, n1w, actq, rd, 1);
  k_gemm<0><<<dim3(24,32),256,0,stream>>>(actq, Wqkv, 2048, 2048, 2048, 3072,
                                          rd, sc+8, qb, kb, vb, nullptr, nullptr, yqkv);
  k_rope<<<20480,256,0,stream>>>(yqkv, pos);
  k_attn<<<dim3(32,32),256,0,stream>>>(yqkv, attn);
  k_rmsq<<<4096,256,0,stream>>>(attn, n1w, actq, rd, 0);
  k_gemm<1><<<dim3(16,32),256,0,stream>>>(actq, Wo, 2048, 2048, 2048, 2048,
                                          rd, sc+11, nullptr, nullptr, nullptr, x, out, nullptr);

  // ---- MLP half (x1 lives in d_out) ----
  k_rmsq<<<4096,256,0,stream>>>(out, n2w, actq, rd, 1);
  k_gemm<2><<<dim3(86,32),256,0,stream>>>(actq, Wgu, 2048, 2048, 2048, 11008,
                                          rd, sc+12, nullptr, nullptr, nullptr, nullptr, nullptr, ygu);
  k_swiglu<<<4096,256,0,stream>>>(ygu, rd);
  k_gemm<1><<<dim3(16,32),256,0,stream>>>(ygu, Wd, 5504, 11008, 5504, 2048,
                                          rd, sc+14, nullptr, nullptr, nullptr, out, out, nullptr);
}

// Round 2
// 1269.827 us; speedup vs baseline: 1.0950x; 1.0950x over previous
//
#include <hip/hip_runtime.h>

typedef unsigned short u16;
typedef unsigned int   u32;

using bf16x8 = __attribute__((ext_vector_type(8))) short;
using f32x4  = __attribute__((ext_vector_type(4))) float;

#define SEQ    2048
#define DIMC   2048
#define TOK    4096
#define QKV_N  3072
#define GU_N   11008
#define MLP_P  5504
#define MLP_R  5461
#define ATT_SCALE 0.08838834764831845f

struct alignas(8) U16x4 { u16 x, y, z, w; };

__device__ __forceinline__ float bf2f(u16 v){ return __uint_as_float(((u32)v) << 16); }
__device__ __forceinline__ u16 f2bf(float f){
  u32 x = __float_as_uint(f);
  u32 r = (x + 0x7fffu + ((x >> 16) & 1u)) >> 16;
  return (u16)r;
}

__device__ __forceinline__ float waveRedSum(float v){
#pragma unroll
  for (int o = 32; o > 0; o >>= 1) v += __shfl_xor(v, o);
  return v;
}
__device__ __forceinline__ float waveRedMax(float v){
#pragma unroll
  for (int o = 32; o > 0; o >>= 1) v = fmaxf(v, __shfl_xor(v, o));
  return v;
}

// async global->LDS, 16B per lane. LDS layout must be base + lane*16.
#define GLD16(gp, lp) __builtin_amdgcn_global_load_lds( \
    (__attribute__((address_space(1))) void*)(gp), \
    (__attribute__((address_space(3))) void*)(lp), 16, 0, 0)

// ---------------- weight scale: sum |w| ----------------
__global__ __launch_bounds__(256) void k_abssum(const float4* __restrict__ w, int n4,
                                                float* __restrict__ slot){
  float s = 0.f;
  for (int i = blockIdx.x*256 + threadIdx.x; i < n4; i += gridDim.x*256){
    float4 v = w[i];
    s += fabsf(v.x) + fabsf(v.y) + fabsf(v.z) + fabsf(v.w);
  }
  s = waveRedSum(s);
  __shared__ float sm[4];
  int lane = threadIdx.x & 63, wv = threadIdx.x >> 6;
  if (lane == 0) sm[wv] = s;
  __syncthreads();
  if (threadIdx.x == 0) atomicAdd(slot, sm[0]+sm[1]+sm[2]+sm[3]);
}

// sums at sc[0..6] -> deq (=clip(mean,1e-5)) at sc[8..14]
__global__ void k_finalize(float* __restrict__ sc){
  if (threadIdx.x == 0){
    const float counts[7] = {4194304.f, 1048576.f, 1048576.f, 4194304.f,
                             11184128.f, 11184128.f, 11184128.f};
    for (int i = 0; i < 7; i++) sc[8+i] = fmaxf(sc[i]/counts[i], 1e-5f);
  }
}

// ---------------- ternary weight quant -> bf16 {-1,0,1} ----------------
__global__ __launch_bounds__(256) void k_wquant(const float4* __restrict__ src,
                                                U16x4* __restrict__ dst, int n4,
                                                const float* __restrict__ deqp){
  float ws = 1.0f / deqp[0];
  for (int i = blockIdx.x*256 + threadIdx.x; i < n4; i += gridDim.x*256){
    float4 v = src[i];
    U16x4 o;
    o.x = f2bf(fminf(fmaxf(rintf(v.x*ws), -1.f), 1.f));
    o.y = f2bf(fminf(fmaxf(rintf(v.y*ws), -1.f), 1.f));
    o.z = f2bf(fminf(fmaxf(rintf(v.z*ws), -1.f), 1.f));
    o.w = f2bf(fminf(fmaxf(rintf(v.w*ws), -1.f), 1.f));
    dst[i] = o;
  }
}

// down_w [2048][5461] -> [2048][5504] padded with zeros
__global__ __launch_bounds__(256) void k_wquant_down(const float* __restrict__ src,
                                                     u16* __restrict__ dst,
                                                     const float* __restrict__ deqp){
  int i = blockIdx.x*256 + threadIdx.x;
  const int total = 2048*MLP_P;
  if (i >= total) return;
  float ws = 1.0f / deqp[0];
  int r = i / MLP_P;
  int c = i - r*MLP_P;
  float t = 0.f;
  if (c < MLP_R) t = fminf(fmaxf(rintf(src[(long)r*MLP_R + c]*ws), -1.f), 1.f);
  dst[i] = f2bf(t);
}

// ---------------- rmsnorm (optional) + act_quant over 2048 ----------------
__global__ __launch_bounds__(256) void k_rmsq(const float* __restrict__ in,
                                              const float* __restrict__ nw,
                                              u16* __restrict__ outq,
                                              float* __restrict__ rowdeq, int do_norm){
  const int row = blockIdx.x, tid = threadIdx.x;
  const float* xp = in + (long)row * DIMC;
  float v[8];
  float ss = 0.f;
#pragma unroll
  for (int j = 0; j < 8; j++){ v[j] = xp[j*256 + tid]; ss += v[j]*v[j]; }
  __shared__ float sm[8];
  int lane = tid & 63, wv = tid >> 6;
  ss = waveRedSum(ss);
  if (lane == 0) sm[wv] = ss;
  __syncthreads();
  float rms = 1.f;
  if (do_norm){
    float tot = sm[0]+sm[1]+sm[2]+sm[3];
    rms = rsqrtf(tot * (1.0f/DIMC) + 1.1920929e-07f);
  }
  float h[8];
  float amax = 0.f;
#pragma unroll
  for (int j = 0; j < 8; j++){
    float hv = v[j];
    if (do_norm) hv = hv * rms * nw[j*256 + tid];
    h[j] = hv;
    amax = fmaxf(amax, fabsf(hv));
  }
  amax = waveRedMax(amax);
  if (lane == 0) sm[4+wv] = amax;
  __syncthreads();
  float gmax = fmaxf(fmaxf(sm[4],sm[5]), fmaxf(sm[6],sm[7]));
  float sc = 127.0f / fmaxf(gmax, 1e-5f);
#pragma unroll
  for (int j = 0; j < 8; j++){
    float q = fminf(fmaxf(rintf(h[j]*sc), -128.f), 127.f);
    outq[(long)row*DIMC + j*256 + tid] = f2bf(q);
  }
  if (tid == 0) rowdeq[row] = 1.0f / sc;
}

// ---------------- RoPE in place on cols [0,2560) of y_qkv ----------------
__global__ __launch_bounds__(256) void k_rope(u16* __restrict__ y, const int* __restrict__ pos_ids){
  int idx = blockIdx.x*256 + threadIdx.x;     // < 4096*1280
  int m = idx / 1280;
  int p = idx - m*1280;
  int c = p*2;
  int i = (c & 127) >> 1;
  float pos = (float)pos_ids[m];
  float inv = expf((float)i * -0.14391156831212787f);  // 10000^(-i/64)
  float f = pos * inv;
  float sn, cs;
  sincosf(f, &sn, &cs);
  u32* pr = (u32*)(y + (long)m*QKV_N + c);
  u32 both = *pr;
  float x0 = bf2f((u16)(both & 0xffffu));
  float x1 = bf2f((u16)(both >> 16));
  u16 o0 = f2bf(x0*cs - x1*sn);
  u16 o1 = f2bf(x1*cs + x0*sn);
  *pr = (u32)o0 | ((u32)o1 << 16);
}

// ---------------- V transpose: yqkv V-section -> VT[b][hk][128][SEQ] ----------------
__global__ __launch_bounds__(256) void k_vtrans(const u16* __restrict__ Y, u16* __restrict__ VT){
  int idx = blockIdx.x*256 + threadIdx.x;   // 1024 blocks -> 262144 threads
  int d  = idx & 127;
  int hk = (idx >> 7) & 3;
  int b  = (idx >> 9) & 1;
  int tg = idx >> 10;                       // 0..255
  int tok0 = tg*8;
  const u16* src = Y + ((long)b*SEQ + tok0)*QKV_N + 2560 + hk*128 + d;
  u16 tmp[8];
#pragma unroll
  for (int e = 0; e < 8; e++) tmp[e] = src[(long)e*QKV_N];
  *(int4*)(VT + (((long)(b*4+hk))*128 + d)*SEQ + tok0) = *(int4*)tmp;
}

// ---------------- GEMM: y = A(bf16-int rows) @ B(bf16-ternary rows)^T ----------------
template<int MODE>
__global__ __launch_bounds__(256) void k_gemm(
    const u16* __restrict__ A, const u16* __restrict__ B,
    int K, int lda, int ldb, int ldc,
    const float* __restrict__ rowdeq, const float* __restrict__ deqp,
    const float* __restrict__ bq, const float* __restrict__ bk, const float* __restrict__ bv,
    const float* __restrict__ resid, float* __restrict__ outF, u16* __restrict__ outB)
{
  __shared__ u16 sA[128*32];
  __shared__ u16 sB[128*32];
  const int tid = threadIdx.x;
  const int lane = tid & 63, wv = tid >> 6;
  const int wr = wv >> 1, wc = wv & 1;
  const long m0 = (long)blockIdx.y * 128;
  const long n0 = (long)blockIdx.x * 128;
  const int r = lane & 15, qq = lane >> 4;

  f32x4 acc[4][4];
#pragma unroll
  for (int i = 0; i < 4; i++)
#pragma unroll
    for (int j = 0; j < 4; j++) acc[i][j] = (f32x4){0.f,0.f,0.f,0.f};

  const int c0 = tid, c1 = tid + 256;
  const u16* gA0 = A + (m0 + (c0>>2))*lda + (c0&3)*8;
  const u16* gA1 = A + (m0 + (c1>>2))*lda + (c1&3)*8;
  const u16* gB0 = B + (n0 + (c0>>2))*ldb + (c0&3)*8;
  const u16* gB1 = B + (n0 + (c1>>2))*ldb + (c1&3)*8;
  u16* lA0 = sA + c0*8; u16* lA1 = sA + c1*8;
  u16* lB0 = sB + c0*8; u16* lB1 = sB + c1*8;

  for (int kt = 0; kt < K; kt += 32){
    __syncthreads();
    GLD16(gA0 + kt, lA0);
    GLD16(gA1 + kt, lA1);
    GLD16(gB0 + kt, lB0);
    GLD16(gB1 + kt, lB1);
    __syncthreads();
    bf16x8 aF[4], bF[4];
#pragma unroll
    for (int i = 0; i < 4; i++) aF[i] = *(const bf16x8*)(sA + (wr*64 + 16*i + r)*32 + qq*8);
#pragma unroll
    for (int j = 0; j < 4; j++) bF[j] = *(const bf16x8*)(sB + (wc*64 + 16*j + r)*32 + qq*8);
#pragma unroll
    for (int i = 0; i < 4; i++)
#pragma unroll
      for (int j = 0; j < 4; j++)
        acc[i][j] = __builtin_amdgcn_mfma_f32_16x16x32_bf16(aF[i], bF[j], acc[i][j], 0, 0, 0);
  }

#pragma unroll
  for (int i = 0; i < 4; i++){
#pragma unroll
    for (int t = 0; t < 4; t++){
      const long row = m0 + wr*64 + 16*i + 4*qq + t;
      const float rdv = rowdeq[row];
#pragma unroll
      for (int j = 0; j < 4; j++){
        const long col = n0 + wc*64 + 16*j + r;
        float vv = acc[i][j][t];
        if (MODE == 0){
          int sec = (col >= 2048) + (col >= 2560);
          float dq = deqp[sec];
          float bias = (sec == 0) ? bq[col] : (sec == 1) ? bk[col-2048] : bv[col-2560];
          outB[row*(long)ldc + col] = f2bf(vv*rdv*dq + bias);
        } else if (MODE == 1){
          outF[row*(long)ldc + col] = vv*rdv*deqp[0] + resid[row*(long)ldc + col];
        } else {
          int sec = (col >= 5504) ? 1 : 0;
          outB[row*(long)ldc + col] = f2bf(vv*rdv*deqp[sec]);
        }
      }
    }
  }
}

// ---------------- flash attention v2 (bf16 MFMA, online softmax) ----------------
// LDS 44KB -> 3 blocks/CU. V comes pre-transposed from global (VT).
// All b128 LDS accesses are bank-uniform (start = 4*(row+colgrp) mod 32).
__global__ __launch_bounds__(256) void k_attn(const u16* __restrict__ Y,
                                              const u16* __restrict__ VT,
                                              float* __restrict__ O)
{
  __shared__ u16 Ks[64][136];    // K tile (also used to stage Q once at start)
  __shared__ u16 VTs[128][72];   // V^T tile: [d][key]
  __shared__ u16 Ps[64][72];     // P tile (C-layout -> A-layout round trip)

  const int qt = 31 - blockIdx.x;          // longest blocks launch first
  const int bh = blockIdx.y;
  const int b = bh >> 4, h = bh & 15, hk = h >> 2;
  const int q0 = qt * 64;
  const int tid = threadIdx.x;
  const int lane = tid & 63, wv = tid >> 6;
  const int r = lane & 15, qq = lane >> 4;
  const long rowbase = (long)b * SEQ;
  const u16* Kbase = Y + rowbase*QKV_N + 2048 + hk*128;
  const u16* Vbase = VT + ((long)(b*4+hk))*128*SEQ;

  // stage Q through the K buffer, pull fragments to registers
  for (int c = tid; c < 1024; c += 256){
    int rw = c >> 4, c8 = c & 15;
    *(int4*)&Ks[rw][c8*8] = *(const int4*)(Y + (rowbase + q0 + rw)*QKV_N + h*128 + c8*8);
  }
  __syncthreads();
  bf16x8 qf[4];
#pragma unroll
  for (int kc = 0; kc < 4; kc++) qf[kc] = *(const bf16x8*)&Ks[wv*16 + r][kc*32 + qq*8];

  f32x4 accO[8];
#pragma unroll
  for (int jn = 0; jn < 8; jn++) accO[jn] = (f32x4){0.f,0.f,0.f,0.f};
  float m_run[4] = {-INFINITY,-INFINITY,-INFINITY,-INFINITY};
  float l_run[4] = {0.f,0.f,0.f,0.f};

  for (int kt = 0; kt <= qt; kt++){
    __syncthreads();
    for (int c = tid; c < 1024; c += 256){
      int rw = c >> 4, c8 = c & 15;
      *(int4*)&Ks[rw][c8*8] = *(const int4*)(Kbase + ((long)(kt*64 + rw))*QKV_N + c8*8);
    }
    for (int c = tid; c < 1024; c += 256){
      int d = c >> 3, g = c & 7;
      *(int4*)&VTs[d][g*8] = *(const int4*)(Vbase + (long)d*SEQ + kt*64 + g*8);
    }
    __syncthreads();

    // S = Q K^T  (A=Q frag, B=K row-major frag; C: col=key, row=q)
    float sv[4][4];
#pragma unroll
    for (int j = 0; j < 4; j++){
      f32x4 a = (f32x4){0.f,0.f,0.f,0.f};
#pragma unroll
      for (int kc = 0; kc < 4; kc++){
        bf16x8 kf = *(const bf16x8*)&Ks[16*j + r][kc*32 + qq*8];
        a = __builtin_amdgcn_mfma_f32_16x16x32_bf16(qf[kc], kf, a, 0, 0, 0);
      }
#pragma unroll
      for (int t = 0; t < 4; t++) sv[j][t] = a[t] * ATT_SCALE;
    }
    if (kt == qt){
#pragma unroll
      for (int j = 0; j < 4; j++){
        int key = kt*64 + 16*j + r;
#pragma unroll
        for (int t = 0; t < 4; t++){
          int qr = q0 + wv*16 + 4*qq + t;
          if (key > qr) sv[j][t] = -INFINITY;
        }
      }
    }
    // online softmax per q-row (rows live in this wave)
#pragma unroll
    for (int t = 0; t < 4; t++){
      float mm = fmaxf(fmaxf(sv[0][t],sv[1][t]), fmaxf(sv[2][t],sv[3][t]));
#pragma unroll
      for (int o = 8; o > 0; o >>= 1) mm = fmaxf(mm, __shfl_xor(mm, o));
      float mnew = fmaxf(m_run[t], mm);
      float alpha = __expf(m_run[t] - mnew);
      m_run[t] = mnew;
      float ps = 0.f;
#pragma unroll
      for (int j = 0; j < 4; j++){
        float p = __expf(sv[j][t] - mnew);
        ps += p;
        Ps[wv*16 + 4*qq + t][16*j + r] = f2bf(p);
      }
#pragma unroll
      for (int o = 8; o > 0; o >>= 1) ps += __shfl_xor(ps, o);
      l_run[t] = l_run[t]*alpha + ps;
#pragma unroll
      for (int jn = 0; jn < 8; jn++) accO[jn][t] *= alpha;
    }
    // O += P V   (A=P frag from LDS, B=V^T row-major frag)
#pragma unroll
    for (int kc = 0; kc < 2; kc++){
      bf16x8 pf = *(const bf16x8*)&Ps[wv*16 + r][kc*32 + qq*8];
#pragma unroll
      for (int jn = 0; jn < 8; jn++){
        bf16x8 vf = *(const bf16x8*)&VTs[16*jn + r][kc*32 + qq*8];
        accO[jn] = __builtin_amdgcn_mfma_f32_16x16x32_bf16(pf, vf, accO[jn], 0, 0, 0);
      }
    }
  }
  float inv[4];
#pragma unroll
  for (int t = 0; t < 4; t++) inv[t] = 1.0f / l_run[t];
#pragma unroll
  for (int jn = 0; jn < 8; jn++){
#pragma unroll
    for (int t = 0; t < 4; t++){
      long row = rowbase + q0 + wv*16 + 4*qq + t;
      O[row*DIMC + h*128 + 16*jn + r] = accO[jn][t]*inv[t];
    }
  }
}

// ---------------- SwiGLU + act_quant in place over y_gu rows ----------------
__global__ __launch_bounds__(256) void k_swiglu(u16* __restrict__ ygu, float* __restrict__ rowdeq){
  const int row = blockIdx.x, tid = threadIdx.x;
  u16* base = ygu + (long)row * GU_N;
  float h[22];
  float amax = 0.f;
#pragma unroll
  for (int it = 0; it < 22; it++){
    int j = it*256 + tid;
    float hv = 0.f;
    if (j < MLP_P){
      float g = bf2f(base[j]);
      float u = bf2f(base[MLP_P + j]);
      hv = g * (1.0f/(1.0f + __expf(-g))) * u;
    }
    h[it] = hv;
    amax = fmaxf(amax, fabsf(hv));
  }
  amax = waveRedMax(amax);
  __shared__ float sm[4];
  int lane = tid & 63, wv = tid >> 6;
  if (lane == 0) sm[wv] = amax;
  __syncthreads();
  float gmax = fmaxf(fmaxf(sm[0],sm[1]), fmaxf(sm[2],sm[3]));
  float sc = 127.0f / fmaxf(gmax, 1e-5f);
#pragma unroll
  for (int it = 0; it < 22; it++){
    int j = it*256 + tid;
    if (j < MLP_P){
      float q = fminf(fmaxf(rintf(h[it]*sc), -128.f), 127.f);
      base[j] = f2bf(q);
    }
  }
  if (tid == 0) rowdeq[row] = 1.0f/sc;
}

extern "C" void kernel_launch(void* const* d_in, const int* in_sizes, int n_in,
                              void* d_out, int out_size, void* d_ws, size_t ws_size,
                              hipStream_t stream)
{
  (void)in_sizes; (void)n_in; (void)out_size; (void)ws_size;
  const float* x   = (const float*)d_in[0];
  const int*   pos = (const int*)d_in[1];
  const float* n1w = (const float*)d_in[2];
  const float* qw  = (const float*)d_in[3];
  const float* qb  = (const float*)d_in[4];
  const float* kw  = (const float*)d_in[5];
  const float* kb  = (const float*)d_in[6];
  const float* vw  = (const float*)d_in[7];
  const float* vb  = (const float*)d_in[8];
  const float* ow  = (const float*)d_in[9];
  const float* n2w = (const float*)d_in[10];
  const float* gw  = (const float*)d_in[11];
  const float* uw  = (const float*)d_in[12];
  const float* dw  = (const float*)d_in[13];
  float* out = (float*)d_out;
  char* ws = (char*)d_ws;

  // workspace layout
  float* sc   = (float*)ws;                 // [0..6] sums, [8..14] deq
  u16* Wqkv   = (u16*)(ws + 256);           // [3072][2048] bf16
  u16* Wo     = (u16*)(ws + 12583168);      // [2048][2048]
  u16* Wgu    = (u16*)(ws + 20971776);      // [11008][2048]
  u16* Wd     = (u16*)(ws + 66060544);      // [2048][5504]
  u16* actq   = (u16*)(ws + 88604928);      // [4096][2048] bf16
  float* rd   = (float*)(ws + 105382144);   // [4096]
  char* xreg  = ws + 105398528;             // big overlay region (90.2 MB)
  u16* yqkv   = (u16*)xreg;                 // [4096][3072] bf16
  float* attn = (float*)(xreg + 25165824);  // [4096][2048] fp32 (ends at +58.7MB)
  u16* vT     = (u16*)(xreg + 58720256);    // [8][128][2048] bf16 (8.4MB)
  u16* ygu    = (u16*)xreg;                 // [4096][11008] bf16 (after attention phase)

  // ---- weight scales + ternary quant ----
  hipMemsetAsync(sc, 0, 64, stream);
  k_abssum<<<512,256,0,stream>>>((const float4*)qw, 4194304/4, sc+0);
  k_abssum<<<512,256,0,stream>>>((const float4*)kw, 1048576/4, sc+1);
  k_abssum<<<512,256,0,stream>>>((const float4*)vw, 1048576/4, sc+2);
  k_abssum<<<512,256,0,stream>>>((const float4*)ow, 4194304/4, sc+3);
  k_abssum<<<512,256,0,stream>>>((const float4*)gw, 11184128/4, sc+4);
  k_abssum<<<512,256,0,stream>>>((const float4*)uw, 11184128/4, sc+5);
  k_abssum<<<512,256,0,stream>>>((const float4*)dw, 11184128/4, sc+6);
  k_finalize<<<1,64,0,stream>>>(sc);
  k_wquant<<<1024,256,0,stream>>>((const float4*)qw, (U16x4*)Wqkv,                4194304/4,  sc+8);
  k_wquant<<<1024,256,0,stream>>>((const float4*)kw, (U16x4*)(Wqkv + 2048l*2048), 1048576/4,  sc+9);
  k_wquant<<<1024,256,0,stream>>>((const float4*)vw, (U16x4*)(Wqkv + 2560l*2048), 1048576/4,  sc+10);
  k_wquant<<<1024,256,0,stream>>>((const float4*)ow, (U16x4*)Wo,                  4194304/4,  sc+11);
  k_wquant<<<1024,256,0,stream>>>((const float4*)gw, (U16x4*)Wgu,                 11184128/4, sc+12);
  k_wquant<<<1024,256,0,stream>>>((const float4*)uw, (U16x4*)(Wgu + 5504l*2048),  11184128/4, sc+13);
  hipMemsetAsync(Wgu + 5461l*2048,        0, 43l*2048*2, stream);
  hipMemsetAsync(Wgu + (5504l+5461)*2048, 0, 43l*2048*2, stream);
  k_wquant_down<<<44032,256,0,stream>>>(dw, Wd, sc+14);

  // ---- attention half ----
  k_rmsq<<<4096,256,0,stream>>>(x, n1w, actq, rd, 1);
  k_gemm<0><<<dim3(24,32),256,0,stream>>>(actq, Wqkv, 2048, 2048, 2048, 3072,
                                          rd, sc+8, qb, kb, vb, nullptr, nullptr, yqkv);
  k_rope<<<20480,256,0,stream>>>(yqkv, pos);
  k_vtrans<<<1024,256,0,stream>>>(yqkv, vT);
  k_attn<<<dim3(32,32),256,0,stream>>>(yqkv, vT, attn);
  k_rmsq<<<4096,256,0,stream>>>(attn, n1w, actq, rd, 0);
  k_gemm<1><<<dim3(16,32),256,0,stream>>>(actq, Wo, 2048, 2048, 2048, 2048,
                                          rd, sc+11, nullptr, nullptr, nullptr, x, out, nullptr);

  // ---- MLP half (x1 lives in d_out) ----
  k_rmsq<<<4096,256,0,stream>>>(out, n2w, actq, rd, 1);
  k_gemm<2><<<dim3(86,32),256,0,stream>>>(actq, Wgu, 2048, 2048, 2048, 11008,
                                          rd, sc+12, nullptr, nullptr, nullptr, nullptr, nullptr, ygu);
  k_swiglu<<<4096,256,0,stream>>>(ygu, rd);
  k_gemm<1><<<dim3(16,32),256,0,stream>>>(ygu, Wd, 5504, 11008, 5504, 2048,
                                          rd, sc+14, nullptr, nullptr, nullptr, out, out, nullptr);
}

// Round 3
// 969.639 us; speedup vs baseline: 1.4340x; 1.3096x over previous
//
#include <hip/hip_runtime.h>

typedef unsigned short u16;
typedef unsigned int   u32;
typedef unsigned char  u8;

using bf16x8 = __attribute__((ext_vector_type(8))) short;
using f32x4  = __attribute__((ext_vector_type(4))) float;
using i32x4  = __attribute__((ext_vector_type(4))) int;

#define SEQ    2048
#define DIMC   2048
#define TOK    4096
#define QKV_N  3072
#define GU_N   11008
#define MLP_P  5504
#define MLP_R  5461
#define ATT_SCALE 0.08838834764831845f

__device__ __forceinline__ float bf2f(u16 v){ return __uint_as_float(((u32)v) << 16); }
__device__ __forceinline__ u16 f2bf(float f){
  u32 x = __float_as_uint(f);
  u32 r = (x + 0x7fffu + ((x >> 16) & 1u)) >> 16;
  return (u16)r;
}

__device__ __forceinline__ float waveRedSum(float v){
#pragma unroll
  for (int o = 32; o > 0; o >>= 1) v += __shfl_xor(v, o);
  return v;
}
__device__ __forceinline__ float waveRedMax(float v){
#pragma unroll
  for (int o = 32; o > 0; o >>= 1) v = fmaxf(v, __shfl_xor(v, o));
  return v;
}

// async global->LDS, 16B per lane. LDS layout must be base + lane*16.
#define GLD16(gp, lp) __builtin_amdgcn_global_load_lds( \
    (__attribute__((address_space(1))) void*)(gp), \
    (__attribute__((address_space(3))) void*)(lp), 16, 0, 0)

// ---------------- weight scale: sum |w| ----------------
__global__ __launch_bounds__(256) void k_abssum(const float4* __restrict__ w, int n4,
                                                float* __restrict__ slot){
  float s = 0.f;
  for (int i = blockIdx.x*256 + threadIdx.x; i < n4; i += gridDim.x*256){
    float4 v = w[i];
    s += fabsf(v.x) + fabsf(v.y) + fabsf(v.z) + fabsf(v.w);
  }
  s = waveRedSum(s);
  __shared__ float sm[4];
  int lane = threadIdx.x & 63, wv = threadIdx.x >> 6;
  if (lane == 0) sm[wv] = s;
  __syncthreads();
  if (threadIdx.x == 0) atomicAdd(slot, sm[0]+sm[1]+sm[2]+sm[3]);
}

// sums at sc[0..6] -> deq (=clip(mean,1e-5)) at sc[8..14]
__global__ void k_finalize(float* __restrict__ sc){
  if (threadIdx.x == 0){
    const float counts[7] = {4194304.f, 1048576.f, 1048576.f, 4194304.f,
                             11184128.f, 11184128.f, 11184128.f};
    for (int i = 0; i < 7; i++) sc[8+i] = fmaxf(sc[i]/counts[i], 1e-5f);
  }
}

// ---------------- ternary weight quant -> packed i8 {-1,0,1} ----------------
__global__ __launch_bounds__(256) void k_wquant(const float4* __restrict__ src,
                                                u32* __restrict__ dst, int n4,
                                                const float* __restrict__ deqp){
  float ws = 1.0f / deqp[0];
  for (int i = blockIdx.x*256 + threadIdx.x; i < n4; i += gridDim.x*256){
    float4 v = src[i];
    int c0 = (int)fminf(fmaxf(rintf(v.x*ws), -1.f), 1.f);
    int c1 = (int)fminf(fmaxf(rintf(v.y*ws), -1.f), 1.f);
    int c2 = (int)fminf(fmaxf(rintf(v.z*ws), -1.f), 1.f);
    int c3 = (int)fminf(fmaxf(rintf(v.w*ws), -1.f), 1.f);
    dst[i] = (u32)(u8)c0 | ((u32)(u8)c1 << 8) | ((u32)(u8)c2 << 16) | ((u32)(u8)c3 << 24);
  }
}

// down_w [2048][5461] fp32 -> [2048][5504] i8 padded with zeros
__global__ __launch_bounds__(256) void k_wquant_down(const float* __restrict__ src,
                                                     u32* __restrict__ dst,
                                                     const float* __restrict__ deqp){
  int i = blockIdx.x*256 + threadIdx.x;          // over 2048*1376 u32s
  const int total = 2048*(MLP_P/4);
  if (i >= total) return;
  float ws = 1.0f / deqp[0];
  int r = i / (MLP_P/4);
  int c4 = (i - r*(MLP_P/4))*4;
  u32 o = 0;
#pragma unroll
  for (int e = 0; e < 4; e++){
    int c = c4 + e;
    int t = 0;
    if (c < MLP_R) t = (int)fminf(fmaxf(rintf(src[(long)r*MLP_R + c]*ws), -1.f), 1.f);
    o |= (u32)(u8)t << (8*e);
  }
  dst[i] = o;
}

// ---------------- rmsnorm (optional) + act_quant over 2048 -> i8 ----------------
__global__ __launch_bounds__(256) void k_rmsq(const float* __restrict__ in,
                                              const float* __restrict__ nw,
                                              char* __restrict__ outq,
                                              float* __restrict__ rowdeq, int do_norm){
  const int row = blockIdx.x, tid = threadIdx.x;
  const float* xp = in + (long)row * DIMC + tid*8;
  float v[8];
  float4 a0 = *(const float4*)xp;
  float4 a1 = *(const float4*)(xp + 4);
  v[0]=a0.x; v[1]=a0.y; v[2]=a0.z; v[3]=a0.w;
  v[4]=a1.x; v[5]=a1.y; v[6]=a1.z; v[7]=a1.w;
  float ss = 0.f;
#pragma unroll
  for (int j = 0; j < 8; j++) ss += v[j]*v[j];
  __shared__ float sm[8];
  int lane = tid & 63, wv = tid >> 6;
  ss = waveRedSum(ss);
  if (lane == 0) sm[wv] = ss;
  __syncthreads();
  float h[8];
  float amax = 0.f;
  if (do_norm){
    float tot = sm[0]+sm[1]+sm[2]+sm[3];
    float rms = rsqrtf(tot * (1.0f/DIMC) + 1.1920929e-07f);
    float4 w0 = *(const float4*)(nw + tid*8);
    float4 w1 = *(const float4*)(nw + tid*8 + 4);
    float wr8[8] = {w0.x,w0.y,w0.z,w0.w,w1.x,w1.y,w1.z,w1.w};
#pragma unroll
    for (int j = 0; j < 8; j++){ h[j] = v[j]*rms*wr8[j]; amax = fmaxf(amax, fabsf(h[j])); }
  } else {
#pragma unroll
    for (int j = 0; j < 8; j++){ h[j] = v[j]; amax = fmaxf(amax, fabsf(h[j])); }
  }
  amax = waveRedMax(amax);
  if (lane == 0) sm[4+wv] = amax;
  __syncthreads();
  float gmax = fmaxf(fmaxf(sm[4],sm[5]), fmaxf(sm[6],sm[7]));
  float sc = 127.0f / fmaxf(gmax, 1e-5f);
  int2 o;
  char* oc = (char*)&o;
#pragma unroll
  for (int j = 0; j < 8; j++)
    oc[j] = (char)(int)fminf(fmaxf(rintf(h[j]*sc), -128.f), 127.f);
  *(int2*)(outq + (long)row*DIMC + tid*8) = o;
  if (tid == 0) rowdeq[row] = 1.0f / sc;
}

// ---------------- RoPE in place on cols [0,2560) of y_qkv ----------------
__global__ __launch_bounds__(256) void k_rope(u16* __restrict__ y, const int* __restrict__ pos_ids){
  int idx = blockIdx.x*256 + threadIdx.x;     // < 4096*1280
  int m = idx / 1280;
  int p = idx - m*1280;
  int c = p*2;
  int i = (c & 127) >> 1;
  float pos = (float)pos_ids[m];
  float inv = expf((float)i * -0.14391156831212787f);  // 10000^(-i/64)
  float f = pos * inv;
  float sn, cs;
  sincosf(f, &sn, &cs);
  u32* pr = (u32*)(y + (long)m*QKV_N + c);
  u32 both = *pr;
  float x0 = bf2f((u16)(both & 0xffffu));
  float x1 = bf2f((u16)(both >> 16));
  u16 o0 = f2bf(x0*cs - x1*sn);
  u16 o1 = f2bf(x1*cs + x0*sn);
  *pr = (u32)o0 | ((u32)o1 << 16);
}

// ---------------- V transpose: yqkv V-section -> VT[b][hk][128][SEQ] ----------------
__global__ __launch_bounds__(256) void k_vtrans(const u16* __restrict__ Y, u16* __restrict__ VT){
  int idx = blockIdx.x*256 + threadIdx.x;
  int d  = idx & 127;
  int hk = (idx >> 7) & 3;
  int b  = (idx >> 9) & 1;
  int tg = idx >> 10;                       // 0..255
  int tok0 = tg*8;
  const u16* src = Y + ((long)b*SEQ + tok0)*QKV_N + 2560 + hk*128 + d;
  u16 tmp[8];
#pragma unroll
  for (int e = 0; e < 8; e++) tmp[e] = src[(long)e*QKV_N];
  *(int4*)(VT + (((long)(b*4+hk))*128 + d)*SEQ + tok0) = *(int4*)tmp;
}

// ---------------- GEMM (i8 MFMA): y = A_i8 @ B_i8^T, exact integer ----------------
// MODE 0: QKV  -> bf16 out + bias, deq by section {q,k,v}, ldc=3072
// MODE 1: fp32 out = acc*rd*deq + resid, ldc=N       (O-proj and Down)
// MODE 2: GU   -> bf16 out, deq by half {gate,up}, ldc=11008
template<int MODE>
__global__ __launch_bounds__(256) void k_gemm(
    const char* __restrict__ A, const char* __restrict__ B,
    int K, int lda, int ldb, int ldc,
    const float* __restrict__ rowdeq, const float* __restrict__ deqp,
    const float* __restrict__ bq, const float* __restrict__ bk, const float* __restrict__ bv,
    const float* __restrict__ resid, float* __restrict__ outF, u16* __restrict__ outB)
{
  __shared__ char sA[128*64];
  __shared__ char sB[128*64];
  const int tid = threadIdx.x;
  const int lane = tid & 63, wv = tid >> 6;
  const int wr = wv >> 1, wc = wv & 1;
  const long m0 = (long)blockIdx.y * 128;
  const long n0 = (long)blockIdx.x * 128;
  const int r = lane & 15, qq = lane >> 4;

  i32x4 acc[4][4];
#pragma unroll
  for (int i = 0; i < 4; i++)
#pragma unroll
    for (int j = 0; j < 4; j++) acc[i][j] = (i32x4){0,0,0,0};

  const int c0 = tid, c1 = tid + 256;
  const char* gA0 = A + (m0 + (c0>>2))*lda + (c0&3)*16;
  const char* gA1 = A + (m0 + (c1>>2))*lda + (c1&3)*16;
  const char* gB0 = B + (n0 + (c0>>2))*ldb + (c0&3)*16;
  const char* gB1 = B + (n0 + (c1>>2))*ldb + (c1&3)*16;
  char* lA0 = sA + c0*16; char* lA1 = sA + c1*16;
  char* lB0 = sB + c0*16; char* lB1 = sB + c1*16;

  for (int kt = 0; kt < K; kt += 64){
    __syncthreads();
    GLD16(gA0 + kt, lA0);
    GLD16(gA1 + kt, lA1);
    GLD16(gB0 + kt, lB0);
    GLD16(gB1 + kt, lB1);
    __syncthreads();
    i32x4 aF[4], bF[4];
#pragma unroll
    for (int i = 0; i < 4; i++) aF[i] = *(const i32x4*)(sA + (wr*64 + 16*i + r)*64 + qq*16);
#pragma unroll
    for (int j = 0; j < 4; j++) bF[j] = *(const i32x4*)(sB + (wc*64 + 16*j + r)*64 + qq*16);
#pragma unroll
    for (int i = 0; i < 4; i++)
#pragma unroll
      for (int j = 0; j < 4; j++)
        acc[i][j] = __builtin_amdgcn_mfma_i32_16x16x64_i8(aF[i], bF[j], acc[i][j], 0, 0, 0);
  }

#pragma unroll
  for (int i = 0; i < 4; i++){
#pragma unroll
    for (int t = 0; t < 4; t++){
      const long row = m0 + wr*64 + 16*i + 4*qq + t;
      const float rdv = rowdeq[row];
#pragma unroll
      for (int j = 0; j < 4; j++){
        const long col = n0 + wc*64 + 16*j + r;
        float vv = (float)acc[i][j][t];
        if (MODE == 0){
          int sec = (col >= 2048) + (col >= 2560);
          float dq = deqp[sec];
          float bias = (sec == 0) ? bq[col] : (sec == 1) ? bk[col-2048] : bv[col-2560];
          outB[row*(long)ldc + col] = f2bf(vv*rdv*dq + bias);
        } else if (MODE == 1){
          outF[row*(long)ldc + col] = vv*rdv*deqp[0] + resid[row*(long)ldc + col];
        } else {
          int sec = (col >= 5504) ? 1 : 0;
          outB[row*(long)ldc + col] = f2bf(vv*rdv*deqp[sec]);
        }
      }
    }
  }
}

// ---------------- flash attention (bf16 MFMA, online softmax) ----------------
__global__ __launch_bounds__(256) void k_attn(const u16* __restrict__ Y,
                                              const u16* __restrict__ VT,
                                              float* __restrict__ O)
{
  __shared__ u16 Ks[64][136];    // K tile (also used to stage Q once at start)
  __shared__ u16 VTs[128][72];   // V^T tile: [d][key]
  __shared__ u16 Ps[64][72];     // P tile (C-layout -> A-layout round trip)

  const int qt = 31 - blockIdx.x;          // longest blocks launch first
  const int bh = blockIdx.y;
  const int b = bh >> 4, h = bh & 15, hk = h >> 2;
  const int q0 = qt * 64;
  const int tid = threadIdx.x;
  const int lane = tid & 63, wv = tid >> 6;
  const int r = lane & 15, qq = lane >> 4;
  const long rowbase = (long)b * SEQ;
  const u16* Kbase = Y + rowbase*QKV_N + 2048 + hk*128;
  const u16* Vbase = VT + ((long)(b*4+hk))*128*SEQ;

  for (int c = tid; c < 1024; c += 256){
    int rw = c >> 4, c8 = c & 15;
    *(int4*)&Ks[rw][c8*8] = *(const int4*)(Y + (rowbase + q0 + rw)*QKV_N + h*128 + c8*8);
  }
  __syncthreads();
  bf16x8 qf[4];
#pragma unroll
  for (int kc = 0; kc < 4; kc++) qf[kc] = *(const bf16x8*)&Ks[wv*16 + r][kc*32 + qq*8];

  f32x4 accO[8];
#pragma unroll
  for (int jn = 0; jn < 8; jn++) accO[jn] = (f32x4){0.f,0.f,0.f,0.f};
  float m_run[4] = {-INFINITY,-INFINITY,-INFINITY,-INFINITY};
  float l_run[4] = {0.f,0.f,0.f,0.f};

  for (int kt = 0; kt <= qt; kt++){
    __syncthreads();
    for (int c = tid; c < 1024; c += 256){
      int rw = c >> 4, c8 = c & 15;
      *(int4*)&Ks[rw][c8*8] = *(const int4*)(Kbase + ((long)(kt*64 + rw))*QKV_N + c8*8);
    }
    for (int c = tid; c < 1024; c += 256){
      int d = c >> 3, g = c & 7;
      *(int4*)&VTs[d][g*8] = *(const int4*)(Vbase + (long)d*SEQ + kt*64 + g*8);
    }
    __syncthreads();

    float sv[4][4];
#pragma unroll
    for (int j = 0; j < 4; j++){
      f32x4 a = (f32x4){0.f,0.f,0.f,0.f};
#pragma unroll
      for (int kc = 0; kc < 4; kc++){
        bf16x8 kf = *(const bf16x8*)&Ks[16*j + r][kc*32 + qq*8];
        a = __builtin_amdgcn_mfma_f32_16x16x32_bf16(qf[kc], kf, a, 0, 0, 0);
      }
#pragma unroll
      for (int t = 0; t < 4; t++) sv[j][t] = a[t] * ATT_SCALE;
    }
    if (kt == qt){
#pragma unroll
      for (int j = 0; j < 4; j++){
        int key = kt*64 + 16*j + r;
#pragma unroll
        for (int t = 0; t < 4; t++){
          int qr = q0 + wv*16 + 4*qq + t;
          if (key > qr) sv[j][t] = -INFINITY;
        }
      }
    }
#pragma unroll
    for (int t = 0; t < 4; t++){
      float mm = fmaxf(fmaxf(sv[0][t],sv[1][t]), fmaxf(sv[2][t],sv[3][t]));
#pragma unroll
      for (int o = 8; o > 0; o >>= 1) mm = fmaxf(mm, __shfl_xor(mm, o));
      float mnew = fmaxf(m_run[t], mm);
      float alpha = __expf(m_run[t] - mnew);
      m_run[t] = mnew;
      float ps = 0.f;
#pragma unroll
      for (int j = 0; j < 4; j++){
        float p = __expf(sv[j][t] - mnew);
        ps += p;
        Ps[wv*16 + 4*qq + t][16*j + r] = f2bf(p);
      }
#pragma unroll
      for (int o = 8; o > 0; o >>= 1) ps += __shfl_xor(ps, o);
      l_run[t] = l_run[t]*alpha + ps;
#pragma unroll
      for (int jn = 0; jn < 8; jn++) accO[jn][t] *= alpha;
    }
#pragma unroll
    for (int kc = 0; kc < 2; kc++){
      bf16x8 pf = *(const bf16x8*)&Ps[wv*16 + r][kc*32 + qq*8];
#pragma unroll
      for (int jn = 0; jn < 8; jn++){
        bf16x8 vf = *(const bf16x8*)&VTs[16*jn + r][kc*32 + qq*8];
        accO[jn] = __builtin_amdgcn_mfma_f32_16x16x32_bf16(pf, vf, accO[jn], 0, 0, 0);
      }
    }
  }
  float inv[4];
#pragma unroll
  for (int t = 0; t < 4; t++) inv[t] = 1.0f / l_run[t];
#pragma unroll
  for (int jn = 0; jn < 8; jn++){
#pragma unroll
    for (int t = 0; t < 4; t++){
      long row = rowbase + q0 + wv*16 + 4*qq + t;
      O[row*DIMC + h*128 + 16*jn + r] = accO[jn][t]*inv[t];
    }
  }
}

// ---------------- SwiGLU + act_quant: ygu bf16 -> i8 [4096][5504] ----------------
__global__ __launch_bounds__(256) void k_swiglu(const u16* __restrict__ ygu,
                                                char* __restrict__ qout,
                                                float* __restrict__ rowdeq){
  const int row = blockIdx.x, tid = threadIdx.x;
  const u16* base = ygu + (long)row * GU_N;
  float h[24];
  float amax = 0.f;
#pragma unroll
  for (int it = 0; it < 3; it++){
    int chunk = it*256 + tid;
    if (chunk < 688){
      int j0 = chunk*8;
      int4 g4 = *(const int4*)(base + j0);
      int4 u4 = *(const int4*)(base + MLP_P + j0);
      const u16* gp = (const u16*)&g4;
      const u16* up = (const u16*)&u4;
#pragma unroll
      for (int e = 0; e < 8; e++){
        float g = bf2f(gp[e]);
        float u = bf2f(up[e]);
        float hv = g * (1.0f/(1.0f + __expf(-g))) * u;
        h[it*8+e] = hv;
        amax = fmaxf(amax, fabsf(hv));
      }
    } else {
#pragma unroll
      for (int e = 0; e < 8; e++) h[it*8+e] = 0.f;
    }
  }
  amax = waveRedMax(amax);
  __shared__ float sm[4];
  int lane = tid & 63, wv = tid >> 6;
  if (lane == 0) sm[wv] = amax;
  __syncthreads();
  float gmax = fmaxf(fmaxf(sm[0],sm[1]), fmaxf(sm[2],sm[3]));
  float sc = 127.0f / fmaxf(gmax, 1e-5f);
#pragma unroll
  for (int it = 0; it < 3; it++){
    int chunk = it*256 + tid;
    if (chunk < 688){
      int j0 = chunk*8;
      int2 o;
      char* oc = (char*)&o;
#pragma unroll
      for (int e = 0; e < 8; e++)
        oc[e] = (char)(int)fminf(fmaxf(rintf(h[it*8+e]*sc), -128.f), 127.f);
      *(int2*)(qout + (long)row*MLP_P + j0) = o;
    }
  }
  if (tid == 0) rowdeq[row] = 1.0f/sc;
}

extern "C" void kernel_launch(void* const* d_in, const int* in_sizes, int n_in,
                              void* d_out, int out_size, void* d_ws, size_t ws_size,
                              hipStream_t stream)
{
  (void)in_sizes; (void)n_in; (void)out_size; (void)ws_size;
  const float* x   = (const float*)d_in[0];
  const int*   pos = (const int*)d_in[1];
  const float* n1w = (const float*)d_in[2];
  const float* qw  = (const float*)d_in[3];
  const float* qb  = (const float*)d_in[4];
  const float* kw  = (const float*)d_in[5];
  const float* kb  = (const float*)d_in[6];
  const float* vw  = (const float*)d_in[7];
  const float* vb  = (const float*)d_in[8];
  const float* ow  = (const float*)d_in[9];
  const float* n2w = (const float*)d_in[10];
  const float* gw  = (const float*)d_in[11];
  const float* uw  = (const float*)d_in[12];
  const float* dw  = (const float*)d_in[13];
  float* out = (float*)d_out;
  char* ws = (char*)d_ws;

  // workspace layout (all offsets multiple of 256)
  float* sc   = (float*)ws;                 // [0..6] sums, [8..14] deq
  char* Wqkv  = ws + 256;                   // [3072][2048] i8   (6.29 MB)
  char* Wo    = ws + 6291712;               // [2048][2048] i8   (4.19 MB)
  char* Wgu   = ws + 10486016;              // [11008][2048] i8  (22.5 MB)
  char* Wd    = ws + 33030400;              // [2048][5504] i8   (11.3 MB)
  char* actq  = ws + 44302592;              // [4096][2048] i8   (8.39 MB)
  char* swq   = ws + 52691200;              // [4096][5504] i8   (22.5 MB)
  float* rd   = (float*)(ws + 75235584);    // [4096] fp32
  char* xreg  = ws + 75252224;              // overlay region (90.2 MB)
  u16* yqkv   = (u16*)xreg;                 // [4096][3072] bf16 (25.2 MB)
  float* attn = (float*)(xreg + 25165824);  // [4096][2048] fp32 (33.6 MB)
  u16* vT     = (u16*)(xreg + 58720256);    // [8][128][2048] bf16 (8.4 MB)
  u16* ygu    = (u16*)xreg;                 // [4096][11008] bf16 (90.2 MB, after attention)

  // ---- weight scales + ternary i8 quant ----
  hipMemsetAsync(sc, 0, 64, stream);
  k_abssum<<<512,256,0,stream>>>((const float4*)qw, 4194304/4, sc+0);
  k_abssum<<<512,256,0,stream>>>((const float4*)kw, 1048576/4, sc+1);
  k_abssum<<<512,256,0,stream>>>((const float4*)vw, 1048576/4, sc+2);
  k_abssum<<<512,256,0,stream>>>((const float4*)ow, 4194304/4, sc+3);
  k_abssum<<<512,256,0,stream>>>((const float4*)gw, 11184128/4, sc+4);
  k_abssum<<<512,256,0,stream>>>((const float4*)uw, 11184128/4, sc+5);
  k_abssum<<<512,256,0,stream>>>((const float4*)dw, 11184128/4, sc+6);
  k_finalize<<<1,64,0,stream>>>(sc);
  k_wquant<<<1024,256,0,stream>>>((const float4*)qw, (u32*)Wqkv,                4194304/4,  sc+8);
  k_wquant<<<1024,256,0,stream>>>((const float4*)kw, (u32*)(Wqkv + 2048l*2048), 1048576/4,  sc+9);
  k_wquant<<<1024,256,0,stream>>>((const float4*)vw, (u32*)(Wqkv + 2560l*2048), 1048576/4,  sc+10);
  k_wquant<<<1024,256,0,stream>>>((const float4*)ow, (u32*)Wo,                  4194304/4,  sc+11);
  k_wquant<<<1024,256,0,stream>>>((const float4*)gw, (u32*)Wgu,                 11184128/4, sc+12);
  k_wquant<<<1024,256,0,stream>>>((const float4*)uw, (u32*)(Wgu + 5504l*2048),  11184128/4, sc+13);
  hipMemsetAsync(Wgu + 5461l*2048,        0, 43l*2048, stream);
  hipMemsetAsync(Wgu + (5504l+5461)*2048, 0, 43l*2048, stream);
  k_wquant_down<<<11008,256,0,stream>>>(dw, (u32*)Wd, sc+14);

  // ---- attention half ----
  k_rmsq<<<4096,256,0,stream>>>(x, n1w, actq, rd, 1);
  k_gemm<0><<<dim3(24,32),256,0,stream>>>(actq, Wqkv, 2048, 2048, 2048, 3072,
                                          rd, sc+8, qb, kb, vb, nullptr, nullptr, yqkv);
  k_rope<<<20480,256,0,stream>>>(yqkv, pos);
  k_vtrans<<<1024,256,0,stream>>>(yqkv, vT);
  k_attn<<<dim3(32,32),256,0,stream>>>(yqkv, vT, attn);
  k_rmsq<<<4096,256,0,stream>>>(attn, n1w, actq, rd, 0);
  k_gemm<1><<<dim3(16,32),256,0,stream>>>(actq, Wo, 2048, 2048, 2048, 2048,
                                          rd, sc+11, nullptr, nullptr, nullptr, x, out, nullptr);

  // ---- MLP half (x1 lives in d_out) ----
  k_rmsq<<<4096,256,0,stream>>>(out, n2w, actq, rd, 1);
  k_gemm<2><<<dim3(86,32),256,0,stream>>>(actq, Wgu, 2048, 2048, 2048, 11008,
                                          rd, sc+12, nullptr, nullptr, nullptr, nullptr, nullptr, ygu);
  k_swiglu<<<4096,256,0,stream>>>(ygu, swq, rd);
  k_gemm<1><<<dim3(16,32),256,0,stream>>>(swq, Wd, 5504, 5504, 5504, 2048,
                                          rd, sc+14, nullptr, nullptr, nullptr, out, out, nullptr);
}

// Round 4
// 852.476 us; speedup vs baseline: 1.6311x; 1.1374x over previous
//
#include <hip/hip_runtime.h>

typedef unsigned short u16;
typedef unsigned int   u32;
typedef unsigned char  u8;

using bf16x8 = __attribute__((ext_vector_type(8))) short;
using f32x4  = __attribute__((ext_vector_type(4))) float;
using i32x4  = __attribute__((ext_vector_type(4))) int;

#define SEQ    2048
#define DIMC   2048
#define TOK    4096
#define QKV_N  3072
#define GU_N   11008
#define MLP_P  5504
#define MLP_R  5461
#define ATT_SCALE 0.08838834764831845f

__device__ __forceinline__ float bf2f(u16 v){ return __uint_as_float(((u32)v) << 16); }
__device__ __forceinline__ u16 f2bf(float f){
  u32 x = __float_as_uint(f);
  u32 r = (x + 0x7fffu + ((x >> 16) & 1u)) >> 16;
  return (u16)r;
}

__device__ __forceinline__ float waveRedSum(float v){
#pragma unroll
  for (int o = 32; o > 0; o >>= 1) v += __shfl_xor(v, o);
  return v;
}
__device__ __forceinline__ float waveRedMax(float v){
#pragma unroll
  for (int o = 32; o > 0; o >>= 1) v = fmaxf(v, __shfl_xor(v, o));
  return v;
}

// async global->LDS, 16B per lane. LDS layout must be base + lane*16.
#define GLD16(gp, lp) __builtin_amdgcn_global_load_lds( \
    (__attribute__((address_space(1))) void*)(gp), \
    (__attribute__((address_space(3))) void*)(lp), 16, 0, 0)

// ---------------- weight scale: sum |w| ----------------
__global__ __launch_bounds__(256) void k_abssum(const float4* __restrict__ w, int n4,
                                                float* __restrict__ slot){
  float s = 0.f;
  for (int i = blockIdx.x*256 + threadIdx.x; i < n4; i += gridDim.x*256){
    float4 v = w[i];
    s += fabsf(v.x) + fabsf(v.y) + fabsf(v.z) + fabsf(v.w);
  }
  s = waveRedSum(s);
  __shared__ float sm[4];
  int lane = threadIdx.x & 63, wv = threadIdx.x >> 6;
  if (lane == 0) sm[wv] = s;
  __syncthreads();
  if (threadIdx.x == 0) atomicAdd(slot, sm[0]+sm[1]+sm[2]+sm[3]);
}

// sums at sc[0..6] -> deq (=clip(mean,1e-5)) at sc[8..14]
__global__ void k_finalize(float* __restrict__ sc){
  if (threadIdx.x == 0){
    const float counts[7] = {4194304.f, 1048576.f, 1048576.f, 4194304.f,
                             11184128.f, 11184128.f, 11184128.f};
    for (int i = 0; i < 7; i++) sc[8+i] = fmaxf(sc[i]/counts[i], 1e-5f);
  }
}

// ---------------- ternary weight quant -> packed i8 {-1,0,1} ----------------
__global__ __launch_bounds__(256) void k_wquant(const float4* __restrict__ src,
                                                u32* __restrict__ dst, int n4,
                                                const float* __restrict__ deqp){
  float ws = 1.0f / deqp[0];
  for (int i = blockIdx.x*256 + threadIdx.x; i < n4; i += gridDim.x*256){
    float4 v = src[i];
    int c0 = (int)fminf(fmaxf(rintf(v.x*ws), -1.f), 1.f);
    int c1 = (int)fminf(fmaxf(rintf(v.y*ws), -1.f), 1.f);
    int c2 = (int)fminf(fmaxf(rintf(v.z*ws), -1.f), 1.f);
    int c3 = (int)fminf(fmaxf(rintf(v.w*ws), -1.f), 1.f);
    dst[i] = (u32)(u8)c0 | ((u32)(u8)c1 << 8) | ((u32)(u8)c2 << 16) | ((u32)(u8)c3 << 24);
  }
}

// down_w [2048][5461] fp32 -> [2048][5504] i8 padded with zeros
__global__ __launch_bounds__(256) void k_wquant_down(const float* __restrict__ src,
                                                     u32* __restrict__ dst,
                                                     const float* __restrict__ deqp){
  int i = blockIdx.x*256 + threadIdx.x;          // over 2048*1376 u32s
  const int total = 2048*(MLP_P/4);
  if (i >= total) return;
  float ws = 1.0f / deqp[0];
  int r = i / (MLP_P/4);
  int c4 = (i - r*(MLP_P/4))*4;
  u32 o = 0;
#pragma unroll
  for (int e = 0; e < 4; e++){
    int c = c4 + e;
    int t = 0;
    if (c < MLP_R) t = (int)fminf(fmaxf(rintf(src[(long)r*MLP_R + c]*ws), -1.f), 1.f);
    o |= (u32)(u8)t << (8*e);
  }
  dst[i] = o;
}

// ---------------- rmsnorm (optional) + act_quant over 2048 -> i8 ----------------
__global__ __launch_bounds__(256) void k_rmsq(const float* __restrict__ in,
                                              const float* __restrict__ nw,
                                              char* __restrict__ outq,
                                              float* __restrict__ rowdeq, int do_norm){
  const int row = blockIdx.x, tid = threadIdx.x;
  const float* xp = in + (long)row * DIMC + tid*8;
  float v[8];
  float4 a0 = *(const float4*)xp;
  float4 a1 = *(const float4*)(xp + 4);
  v[0]=a0.x; v[1]=a0.y; v[2]=a0.z; v[3]=a0.w;
  v[4]=a1.x; v[5]=a1.y; v[6]=a1.z; v[7]=a1.w;
  float ss = 0.f;
#pragma unroll
  for (int j = 0; j < 8; j++) ss += v[j]*v[j];
  __shared__ float sm[8];
  int lane = tid & 63, wv = tid >> 6;
  ss = waveRedSum(ss);
  if (lane == 0) sm[wv] = ss;
  __syncthreads();
  float h[8];
  float amax = 0.f;
  if (do_norm){
    float tot = sm[0]+sm[1]+sm[2]+sm[3];
    float rms = rsqrtf(tot * (1.0f/DIMC) + 1.1920929e-07f);
    float4 w0 = *(const float4*)(nw + tid*8);
    float4 w1 = *(const float4*)(nw + tid*8 + 4);
    float wr8[8] = {w0.x,w0.y,w0.z,w0.w,w1.x,w1.y,w1.z,w1.w};
#pragma unroll
    for (int j = 0; j < 8; j++){ h[j] = v[j]*rms*wr8[j]; amax = fmaxf(amax, fabsf(h[j])); }
  } else {
#pragma unroll
    for (int j = 0; j < 8; j++){ h[j] = v[j]; amax = fmaxf(amax, fabsf(h[j])); }
  }
  amax = waveRedMax(amax);
  if (lane == 0) sm[4+wv] = amax;
  __syncthreads();
  float gmax = fmaxf(fmaxf(sm[4],sm[5]), fmaxf(sm[6],sm[7]));
  float sc = 127.0f / fmaxf(gmax, 1e-5f);
  int2 o;
  char* oc = (char*)&o;
#pragma unroll
  for (int j = 0; j < 8; j++)
    oc[j] = (char)(int)fminf(fmaxf(rintf(h[j]*sc), -128.f), 127.f);
  *(int2*)(outq + (long)row*DIMC + tid*8) = o;
  if (tid == 0) rowdeq[row] = 1.0f / sc;
}

// ---------------- RoPE in place on cols [0,2560) of y_qkv ----------------
__global__ __launch_bounds__(256) void k_rope(u16* __restrict__ y, const int* __restrict__ pos_ids){
  int idx = blockIdx.x*256 + threadIdx.x;     // < 4096*1280
  int m = idx / 1280;
  int p = idx - m*1280;
  int c = p*2;
  int i = (c & 127) >> 1;
  float pos = (float)pos_ids[m];
  float inv = expf((float)i * -0.14391156831212787f);  // 10000^(-i/64)
  float f = pos * inv;
  float sn, cs;
  sincosf(f, &sn, &cs);
  u32* pr = (u32*)(y + (long)m*QKV_N + c);
  u32 both = *pr;
  float x0 = bf2f((u16)(both & 0xffffu));
  float x1 = bf2f((u16)(both >> 16));
  u16 o0 = f2bf(x0*cs - x1*sn);
  u16 o1 = f2bf(x1*cs + x0*sn);
  *pr = (u32)o0 | ((u32)o1 << 16);
}

// ---------------- V transpose: yqkv V-section -> VT[b][hk][128][SEQ] ----------------
__global__ __launch_bounds__(256) void k_vtrans(const u16* __restrict__ Y, u16* __restrict__ VT){
  int idx = blockIdx.x*256 + threadIdx.x;
  int d  = idx & 127;
  int hk = (idx >> 7) & 3;
  int b  = (idx >> 9) & 1;
  int tg = idx >> 10;                       // 0..255
  int tok0 = tg*8;
  const u16* src = Y + ((long)b*SEQ + tok0)*QKV_N + 2560 + hk*128 + d;
  u16 tmp[8];
#pragma unroll
  for (int e = 0; e < 8; e++) tmp[e] = src[(long)e*QKV_N];
  *(int4*)(VT + (((long)(b*4+hk))*128 + d)*SEQ + tok0) = *(int4*)tmp;
}

// ---------------- GEMM (i8 MFMA): y = A_i8 @ B_i8^T, exact integer ----------------
// MODE 0: QKV  -> bf16 out + bias, deq by section {q,k,v}, ldc=3072
// MODE 1: fp32 out = acc*rd*deq + resid, ldc=N       (O-proj and Down)
// MODE 2: GU   -> bf16 out, deq by half {gate,up}, ldc=11008
template<int MODE>
__global__ __launch_bounds__(256) void k_gemm(
    const char* __restrict__ A, const char* __restrict__ B,
    int K, int lda, int ldb, int ldc,
    const float* __restrict__ rowdeq, const float* __restrict__ deqp,
    const float* __restrict__ bq, const float* __restrict__ bk, const float* __restrict__ bv,
    const float* __restrict__ resid, float* __restrict__ outF, u16* __restrict__ outB)
{
  __shared__ char sA[128*64];
  __shared__ char sB[128*64];
  const int tid = threadIdx.x;
  const int lane = tid & 63, wv = tid >> 6;
  const int wr = wv >> 1, wc = wv & 1;
  const long m0 = (long)blockIdx.y * 128;
  const long n0 = (long)blockIdx.x * 128;
  const int r = lane & 15, qq = lane >> 4;

  i32x4 acc[4][4];
#pragma unroll
  for (int i = 0; i < 4; i++)
#pragma unroll
    for (int j = 0; j < 4; j++) acc[i][j] = (i32x4){0,0,0,0};

  const int c0 = tid, c1 = tid + 256;
  const char* gA0 = A + (m0 + (c0>>2))*lda + (c0&3)*16;
  const char* gA1 = A + (m0 + (c1>>2))*lda + (c1&3)*16;
  const char* gB0 = B + (n0 + (c0>>2))*ldb + (c0&3)*16;
  const char* gB1 = B + (n0 + (c1>>2))*ldb + (c1&3)*16;
  char* lA0 = sA + c0*16; char* lA1 = sA + c1*16;
  char* lB0 = sB + c0*16; char* lB1 = sB + c1*16;

  for (int kt = 0; kt < K; kt += 64){
    __syncthreads();
    GLD16(gA0 + kt, lA0);
    GLD16(gA1 + kt, lA1);
    GLD16(gB0 + kt, lB0);
    GLD16(gB1 + kt, lB1);
    __syncthreads();
    i32x4 aF[4], bF[4];
#pragma unroll
    for (int i = 0; i < 4; i++) aF[i] = *(const i32x4*)(sA + (wr*64 + 16*i + r)*64 + qq*16);
#pragma unroll
    for (int j = 0; j < 4; j++) bF[j] = *(const i32x4*)(sB + (wc*64 + 16*j + r)*64 + qq*16);
#pragma unroll
    for (int i = 0; i < 4; i++)
#pragma unroll
      for (int j = 0; j < 4; j++)
        acc[i][j] = __builtin_amdgcn_mfma_i32_16x16x64_i8(aF[i], bF[j], acc[i][j], 0, 0, 0);
  }

#pragma unroll
  for (int i = 0; i < 4; i++){
#pragma unroll
    for (int t = 0; t < 4; t++){
      const long row = m0 + wr*64 + 16*i + 4*qq + t;
      const float rdv = rowdeq[row];
#pragma unroll
      for (int j = 0; j < 4; j++){
        const long col = n0 + wc*64 + 16*j + r;
        float vv = (float)acc[i][j][t];
        if (MODE == 0){
          int sec = (col >= 2048) + (col >= 2560);
          float dq = deqp[sec];
          float bias = (sec == 0) ? bq[col] : (sec == 1) ? bk[col-2048] : bv[col-2560];
          outB[row*(long)ldc + col] = f2bf(vv*rdv*dq + bias);
        } else if (MODE == 1){
          outF[row*(long)ldc + col] = vv*rdv*deqp[0] + resid[row*(long)ldc + col];
        } else {
          int sec = (col >= 5504) ? 1 : 0;
          outB[row*(long)ldc + col] = f2bf(vv*rdv*deqp[sec]);
        }
      }
    }
  }
}

// ---------------- flash attention v3: paired q-tiles for perfect balance ----------------
// Block p handles q-tiles (31-p) then (p): total work = 33 tile-iters for EVERY block.
// Grid 16x32 = 512 equal blocks -> 2 blocks/CU co-resident, no causal tail.
__global__ __launch_bounds__(256) void k_attn(const u16* __restrict__ Y,
                                              const u16* __restrict__ VT,
                                              float* __restrict__ O)
{
  __shared__ u16 Ks[64][136];    // K tile (also stages Q at phase start)
  __shared__ u16 VTs[128][72];   // V^T tile: [d][key]
  __shared__ u16 Ps[64][72];     // P tile (C-layout -> A-layout round trip, wave-private rows)

  const int pp = blockIdx.x;               // 0..15
  const int bh = blockIdx.y;
  const int b = bh >> 4, h = bh & 15, hk = h >> 2;
  const int tid = threadIdx.x;
  const int lane = tid & 63, wv = tid >> 6;
  const int r = lane & 15, qq = lane >> 4;
  const long rowbase = (long)b * SEQ;
  const u16* Kbase = Y + rowbase*QKV_N + 2048 + hk*128;
  const u16* Vbase = VT + ((long)(b*4+hk))*128*SEQ;

  for (int ph = 0; ph < 2; ph++){
    const int qt = ph ? pp : 31 - pp;
    const int q0 = qt * 64;

    // stage Q through the K buffer, pull fragments to registers
    __syncthreads();
    for (int c = tid; c < 1024; c += 256){
      int rw = c >> 4, c8 = c & 15;
      *(int4*)&Ks[rw][c8*8] = *(const int4*)(Y + (rowbase + q0 + rw)*QKV_N + h*128 + c8*8);
    }
    __syncthreads();
    bf16x8 qf[4];
#pragma unroll
    for (int kc = 0; kc < 4; kc++) qf[kc] = *(const bf16x8*)&Ks[wv*16 + r][kc*32 + qq*8];

    f32x4 accO[8];
#pragma unroll
    for (int jn = 0; jn < 8; jn++) accO[jn] = (f32x4){0.f,0.f,0.f,0.f};
    float m_run[4] = {-INFINITY,-INFINITY,-INFINITY,-INFINITY};
    float l_run[4] = {0.f,0.f,0.f,0.f};

    for (int kt = 0; kt <= qt; kt++){
      __syncthreads();
      for (int c = tid; c < 1024; c += 256){
        int rw = c >> 4, c8 = c & 15;
        *(int4*)&Ks[rw][c8*8] = *(const int4*)(Kbase + ((long)(kt*64 + rw))*QKV_N + c8*8);
      }
      for (int c = tid; c < 1024; c += 256){
        int d = c >> 3, g = c & 7;
        *(int4*)&VTs[d][g*8] = *(const int4*)(Vbase + (long)d*SEQ + kt*64 + g*8);
      }
      __syncthreads();

      // S = Q K^T
      float sv[4][4];
#pragma unroll
      for (int j = 0; j < 4; j++){
        f32x4 a = (f32x4){0.f,0.f,0.f,0.f};
#pragma unroll
        for (int kc = 0; kc < 4; kc++){
          bf16x8 kf = *(const bf16x8*)&Ks[16*j + r][kc*32 + qq*8];
          a = __builtin_amdgcn_mfma_f32_16x16x32_bf16(qf[kc], kf, a, 0, 0, 0);
        }
#pragma unroll
        for (int t = 0; t < 4; t++) sv[j][t] = a[t] * ATT_SCALE;
      }
      if (kt == qt){
#pragma unroll
        for (int j = 0; j < 4; j++){
          int key = kt*64 + 16*j + r;
#pragma unroll
          for (int t = 0; t < 4; t++){
            int qr = q0 + wv*16 + 4*qq + t;
            if (key > qr) sv[j][t] = -INFINITY;
          }
        }
      }
      // online softmax per q-row
#pragma unroll
      for (int t = 0; t < 4; t++){
        float mm = fmaxf(fmaxf(sv[0][t],sv[1][t]), fmaxf(sv[2][t],sv[3][t]));
#pragma unroll
        for (int o = 8; o > 0; o >>= 1) mm = fmaxf(mm, __shfl_xor(mm, o));
        float mnew = fmaxf(m_run[t], mm);
        float alpha = __expf(m_run[t] - mnew);
        m_run[t] = mnew;
        float ps = 0.f;
#pragma unroll
        for (int j = 0; j < 4; j++){
          float p = __expf(sv[j][t] - mnew);
          ps += p;
          Ps[wv*16 + 4*qq + t][16*j + r] = f2bf(p);
        }
#pragma unroll
        for (int o = 8; o > 0; o >>= 1) ps += __shfl_xor(ps, o);
        l_run[t] = l_run[t]*alpha + ps;
#pragma unroll
        for (int jn = 0; jn < 8; jn++) accO[jn][t] *= alpha;
      }
      // O += P V
#pragma unroll
      for (int kc = 0; kc < 2; kc++){
        bf16x8 pf = *(const bf16x8*)&Ps[wv*16 + r][kc*32 + qq*8];
#pragma unroll
        for (int jn = 0; jn < 8; jn++){
          bf16x8 vf = *(const bf16x8*)&VTs[16*jn + r][kc*32 + qq*8];
          accO[jn] = __builtin_amdgcn_mfma_f32_16x16x32_bf16(pf, vf, accO[jn], 0, 0, 0);
        }
      }
    }
    float inv[4];
#pragma unroll
    for (int t = 0; t < 4; t++) inv[t] = 1.0f / l_run[t];
#pragma unroll
    for (int jn = 0; jn < 8; jn++){
#pragma unroll
      for (int t = 0; t < 4; t++){
        long row = rowbase + q0 + wv*16 + 4*qq + t;
        O[row*DIMC + h*128 + 16*jn + r] = accO[jn][t]*inv[t];
      }
    }
  }
}

// ---------------- SwiGLU + act_quant: ygu bf16 -> i8 [4096][5504] ----------------
__global__ __launch_bounds__(256) void k_swiglu(const u16* __restrict__ ygu,
                                                char* __restrict__ qout,
                                                float* __restrict__ rowdeq){
  const int row = blockIdx.x, tid = threadIdx.x;
  const u16* base = ygu + (long)row * GU_N;
  float h[24];
  float amax = 0.f;
#pragma unroll
  for (int it = 0; it < 3; it++){
    int chunk = it*256 + tid;
    if (chunk < 688){
      int j0 = chunk*8;
      int4 g4 = *(const int4*)(base + j0);
      int4 u4 = *(const int4*)(base + MLP_P + j0);
      const u16* gp = (const u16*)&g4;
      const u16* up = (const u16*)&u4;
#pragma unroll
      for (int e = 0; e < 8; e++){
        float g = bf2f(gp[e]);
        float u = bf2f(up[e]);
        float hv = g * (1.0f/(1.0f + __expf(-g))) * u;
        h[it*8+e] = hv;
        amax = fmaxf(amax, fabsf(hv));
      }
    } else {
#pragma unroll
      for (int e = 0; e < 8; e++) h[it*8+e] = 0.f;
    }
  }
  amax = waveRedMax(amax);
  __shared__ float sm[4];
  int lane = tid & 63, wv = tid >> 6;
  if (lane == 0) sm[wv] = amax;
  __syncthreads();
  float gmax = fmaxf(fmaxf(sm[0],sm[1]), fmaxf(sm[2],sm[3]));
  float sc = 127.0f / fmaxf(gmax, 1e-5f);
#pragma unroll
  for (int it = 0; it < 3; it++){
    int chunk = it*256 + tid;
    if (chunk < 688){
      int j0 = chunk*8;
      int2 o;
      char* oc = (char*)&o;
#pragma unroll
      for (int e = 0; e < 8; e++)
        oc[e] = (char)(int)fminf(fmaxf(rintf(h[it*8+e]*sc), -128.f), 127.f);
      *(int2*)(qout + (long)row*MLP_P + j0) = o;
    }
  }
  if (tid == 0) rowdeq[row] = 1.0f/sc;
}

extern "C" void kernel_launch(void* const* d_in, const int* in_sizes, int n_in,
                              void* d_out, int out_size, void* d_ws, size_t ws_size,
                              hipStream_t stream)
{
  (void)in_sizes; (void)n_in; (void)out_size; (void)ws_size;
  const float* x   = (const float*)d_in[0];
  const int*   pos = (const int*)d_in[1];
  const float* n1w = (const float*)d_in[2];
  const float* qw  = (const float*)d_in[3];
  const float* qb  = (const float*)d_in[4];
  const float* kw  = (const float*)d_in[5];
  const float* kb  = (const float*)d_in[6];
  const float* vw  = (const float*)d_in[7];
  const float* vb  = (const float*)d_in[8];
  const float* ow  = (const float*)d_in[9];
  const float* n2w = (const float*)d_in[10];
  const float* gw  = (const float*)d_in[11];
  const float* uw  = (const float*)d_in[12];
  const float* dw  = (const float*)d_in[13];
  float* out = (float*)d_out;
  char* ws = (char*)d_ws;

  // workspace layout (all offsets multiple of 256)
  float* sc   = (float*)ws;                 // [0..6] sums, [8..14] deq
  char* Wqkv  = ws + 256;                   // [3072][2048] i8   (6.29 MB)
  char* Wo    = ws + 6291712;               // [2048][2048] i8   (4.19 MB)
  char* Wgu   = ws + 10486016;              // [11008][2048] i8  (22.5 MB)
  char* Wd    = ws + 33030400;              // [2048][5504] i8   (11.3 MB)
  char* actq  = ws + 44302592;              // [4096][2048] i8   (8.39 MB)
  char* swq   = ws + 52691200;              // [4096][5504] i8   (22.5 MB)
  float* rd   = (float*)(ws + 75235584);    // [4096] fp32
  char* xreg  = ws + 75252224;              // overlay region (90.2 MB)
  u16* yqkv   = (u16*)xreg;                 // [4096][3072] bf16 (25.2 MB)
  float* attn = (float*)(xreg + 25165824);  // [4096][2048] fp32 (33.6 MB)
  u16* vT     = (u16*)(xreg + 58720256);    // [8][128][2048] bf16 (8.4 MB)
  u16* ygu    = (u16*)xreg;                 // [4096][11008] bf16 (90.2 MB, after attention)

  // ---- weight scales + ternary i8 quant ----
  hipMemsetAsync(sc, 0, 64, stream);
  k_abssum<<<512,256,0,stream>>>((const float4*)qw, 4194304/4, sc+0);
  k_abssum<<<512,256,0,stream>>>((const float4*)kw, 1048576/4, sc+1);
  k_abssum<<<512,256,0,stream>>>((const float4*)vw, 1048576/4, sc+2);
  k_abssum<<<512,256,0,stream>>>((const float4*)ow, 4194304/4, sc+3);
  k_abssum<<<512,256,0,stream>>>((const float4*)gw, 11184128/4, sc+4);
  k_abssum<<<512,256,0,stream>>>((const float4*)uw, 11184128/4, sc+5);
  k_abssum<<<512,256,0,stream>>>((const float4*)dw, 11184128/4, sc+6);
  k_finalize<<<1,64,0,stream>>>(sc);
  k_wquant<<<1024,256,0,stream>>>((const float4*)qw, (u32*)Wqkv,                4194304/4,  sc+8);
  k_wquant<<<1024,256,0,stream>>>((const float4*)kw, (u32*)(Wqkv + 2048l*2048), 1048576/4,  sc+9);
  k_wquant<<<1024,256,0,stream>>>((const float4*)vw, (u32*)(Wqkv + 2560l*2048), 1048576/4,  sc+10);
  k_wquant<<<1024,256,0,stream>>>((const float4*)ow, (u32*)Wo,                  4194304/4,  sc+11);
  k_wquant<<<1024,256,0,stream>>>((const float4*)gw, (u32*)Wgu,                 11184128/4, sc+12);
  k_wquant<<<1024,256,0,stream>>>((const float4*)uw, (u32*)(Wgu + 5504l*2048),  11184128/4, sc+13);
  hipMemsetAsync(Wgu + 5461l*2048,        0, 43l*2048, stream);
  hipMemsetAsync(Wgu + (5504l+5461)*2048, 0, 43l*2048, stream);
  k_wquant_down<<<11008,256,0,stream>>>(dw, (u32*)Wd, sc+14);

  // ---- attention half ----
  k_rmsq<<<4096,256,0,stream>>>(x, n1w, actq, rd, 1);
  k_gemm<0><<<dim3(24,32),256,0,stream>>>(actq, Wqkv, 2048, 2048, 2048, 3072,
                                          rd, sc+8, qb, kb, vb, nullptr, nullptr, yqkv);
  k_rope<<<20480,256,0,stream>>>(yqkv, pos);
  k_vtrans<<<1024,256,0,stream>>>(yqkv, vT);
  k_attn<<<dim3(16,32),256,0,stream>>>(yqkv, vT, attn);
  k_rmsq<<<4096,256,0,stream>>>(attn, n1w, actq, rd, 0);
  k_gemm<1><<<dim3(16,32),256,0,stream>>>(actq, Wo, 2048, 2048, 2048, 2048,
                                          rd, sc+11, nullptr, nullptr, nullptr, x, out, nullptr);

  // ---- MLP half (x1 lives in d_out) ----
  k_rmsq<<<4096,256,0,stream>>>(out, n2w, actq, rd, 1);
  k_gemm<2><<<dim3(86,32),256,0,stream>>>(actq, Wgu, 2048, 2048, 2048, 11008,
                                          rd, sc+12, nullptr, nullptr, nullptr, nullptr, nullptr, ygu);
  k_swiglu<<<4096,256,0,stream>>>(ygu, swq, rd);
  k_gemm<1><<<dim3(16,32),256,0,stream>>>(swq, Wd, 5504, 5504, 5504, 2048,
                                          rd, sc+14, nullptr, nullptr, nullptr, out, out, nullptr);
}

// Round 5
// 730.104 us; speedup vs baseline: 1.9045x; 1.1676x over previous
//
#include <hip/hip_runtime.h>

typedef unsigned short u16;
typedef unsigned int   u32;
typedef unsigned char  u8;

using bf16x8 = __attribute__((ext_vector_type(8))) short;
using f32x4  = __attribute__((ext_vector_type(4))) float;
using i32x4  = __attribute__((ext_vector_type(4))) int;

#define SEQ    2048
#define DIMC   2048
#define TOK    4096
#define QKV_N  3072
#define GU_N   11008
#define MLP_P  5504
#define MLP_R  5461
#define ATT_SCALE 0.08838834764831845f

__device__ __forceinline__ float bf2f(u16 v){ return __uint_as_float(((u32)v) << 16); }
__device__ __forceinline__ u16 f2bf(float f){
  u32 x = __float_as_uint(f);
  u32 r = (x + 0x7fffu + ((x >> 16) & 1u)) >> 16;
  return (u16)r;
}

__device__ __forceinline__ float waveRedSum(float v){
#pragma unroll
  for (int o = 32; o > 0; o >>= 1) v += __shfl_xor(v, o);
  return v;
}
__device__ __forceinline__ float waveRedMax(float v){
#pragma unroll
  for (int o = 32; o > 0; o >>= 1) v = fmaxf(v, __shfl_xor(v, o));
  return v;
}

// async global->LDS, 16B per lane. LDS dest is wave-uniform base + lane*16.
#define GLD16(gp, lp) __builtin_amdgcn_global_load_lds( \
    (__attribute__((address_space(1))) void*)(gp), \
    (__attribute__((address_space(3))) void*)(lp), 16, 0, 0)

// ---------------- fused weight abs-sums (7 regions in one dispatch) ----------------
__global__ __launch_bounds__(256) void k_abssum7(
    const float4* __restrict__ w0, const float4* __restrict__ w1,
    const float4* __restrict__ w2, const float4* __restrict__ w3,
    const float4* __restrict__ w4, const float4* __restrict__ w5,
    const float4* __restrict__ w6, float* __restrict__ sc){
  const int rg = blockIdx.y;
  const float4* w = rg==0?w0: rg==1?w1: rg==2?w2: rg==3?w3: rg==4?w4: rg==5?w5: w6;
  const int n4 = (rg==0||rg==3) ? 1048576 : (rg<4 ? 262144 : 2796032);
  float s = 0.f;
  for (int i = blockIdx.x*256 + threadIdx.x; i < n4; i += gridDim.x*256){
    float4 v = w[i];
    s += fabsf(v.x) + fabsf(v.y) + fabsf(v.z) + fabsf(v.w);
  }
  s = waveRedSum(s);
  __shared__ float sm[4];
  int lane = threadIdx.x & 63, wv = threadIdx.x >> 6;
  if (lane == 0) sm[wv] = s;
  __syncthreads();
  if (threadIdx.x == 0) atomicAdd(sc + rg, sm[0]+sm[1]+sm[2]+sm[3]);
}

// sums at sc[0..6] -> deq (=clip(mean,1e-5)) at sc[8..14]
__global__ void k_finalize(float* __restrict__ sc){
  if (threadIdx.x == 0){
    const float counts[7] = {4194304.f, 1048576.f, 1048576.f, 4194304.f,
                             11184128.f, 11184128.f, 11184128.f};
    for (int i = 0; i < 7; i++) sc[8+i] = fmaxf(sc[i]/counts[i], 1e-5f);
  }
}

// ---------------- fused ternary weight quant (6 regions) -> packed i8 ----------------
__global__ __launch_bounds__(256) void k_wquant6(
    const float4* __restrict__ w0, const float4* __restrict__ w1,
    const float4* __restrict__ w2, const float4* __restrict__ w3,
    const float4* __restrict__ w4, const float4* __restrict__ w5,
    u32* __restrict__ d0, u32* __restrict__ d1, u32* __restrict__ d2,
    u32* __restrict__ d3, u32* __restrict__ d4, u32* __restrict__ d5,
    const float* __restrict__ sc){
  const int rg = blockIdx.y;
  const float4* src = rg==0?w0: rg==1?w1: rg==2?w2: rg==3?w3: rg==4?w4: w5;
  u32* dst = rg==0?d0: rg==1?d1: rg==2?d2: rg==3?d3: rg==4?d4: d5;
  const int n4 = (rg==0||rg==3) ? 1048576 : (rg<4 ? 262144 : 2796032);
  float ws = 1.0f / sc[8+rg];
  for (int i = blockIdx.x*256 + threadIdx.x; i < n4; i += gridDim.x*256){
    float4 v = src[i];
    int c0 = (int)fminf(fmaxf(rintf(v.x*ws), -1.f), 1.f);
    int c1 = (int)fminf(fmaxf(rintf(v.y*ws), -1.f), 1.f);
    int c2 = (int)fminf(fmaxf(rintf(v.z*ws), -1.f), 1.f);
    int c3 = (int)fminf(fmaxf(rintf(v.w*ws), -1.f), 1.f);
    dst[i] = (u32)(u8)c0 | ((u32)(u8)c1 << 8) | ((u32)(u8)c2 << 16) | ((u32)(u8)c3 << 24);
  }
}

// down_w [2048][5461] fp32 -> [2048][5504] i8 padded with zeros
__global__ __launch_bounds__(256) void k_wquant_down(const float* __restrict__ src,
                                                     u32* __restrict__ dst,
                                                     const float* __restrict__ deqp){
  int i = blockIdx.x*256 + threadIdx.x;
  const int total = 2048*(MLP_P/4);
  if (i >= total) return;
  float ws = 1.0f / deqp[0];
  int r = i / (MLP_P/4);
  int c4 = (i - r*(MLP_P/4))*4;
  u32 o = 0;
#pragma unroll
  for (int e = 0; e < 4; e++){
    int c = c4 + e;
    int t = 0;
    if (c < MLP_R) t = (int)fminf(fmaxf(rintf(src[(long)r*MLP_R + c]*ws), -1.f), 1.f);
    o |= (u32)(u8)t << (8*e);
  }
  dst[i] = o;
}

// ---------------- rmsnorm (optional) + act_quant over 2048 -> i8 ----------------
__global__ __launch_bounds__(256) void k_rmsq(const float* __restrict__ in,
                                              const float* __restrict__ nw,
                                              char* __restrict__ outq,
                                              float* __restrict__ rowdeq, int do_norm){
  const int row = blockIdx.x, tid = threadIdx.x;
  const float* xp = in + (long)row * DIMC + tid*8;
  float v[8];
  float4 a0 = *(const float4*)xp;
  float4 a1 = *(const float4*)(xp + 4);
  v[0]=a0.x; v[1]=a0.y; v[2]=a0.z; v[3]=a0.w;
  v[4]=a1.x; v[5]=a1.y; v[6]=a1.z; v[7]=a1.w;
  float ss = 0.f;
#pragma unroll
  for (int j = 0; j < 8; j++) ss += v[j]*v[j];
  __shared__ float sm[8];
  int lane = tid & 63, wv = tid >> 6;
  ss = waveRedSum(ss);
  if (lane == 0) sm[wv] = ss;
  __syncthreads();
  float h[8];
  float amax = 0.f;
  if (do_norm){
    float tot = sm[0]+sm[1]+sm[2]+sm[3];
    float rms = rsqrtf(tot * (1.0f/DIMC) + 1.1920929e-07f);
    float4 w0 = *(const float4*)(nw + tid*8);
    float4 w1 = *(const float4*)(nw + tid*8 + 4);
    float wr8[8] = {w0.x,w0.y,w0.z,w0.w,w1.x,w1.y,w1.z,w1.w};
#pragma unroll
    for (int j = 0; j < 8; j++){ h[j] = v[j]*rms*wr8[j]; amax = fmaxf(amax, fabsf(h[j])); }
  } else {
#pragma unroll
    for (int j = 0; j < 8; j++){ h[j] = v[j]; amax = fmaxf(amax, fabsf(h[j])); }
  }
  amax = waveRedMax(amax);
  if (lane == 0) sm[4+wv] = amax;
  __syncthreads();
  float gmax = fmaxf(fmaxf(sm[4],sm[5]), fmaxf(sm[6],sm[7]));
  float sc = 127.0f / fmaxf(gmax, 1e-5f);
  int2 o;
  char* oc = (char*)&o;
#pragma unroll
  for (int j = 0; j < 8; j++)
    oc[j] = (char)(int)fminf(fmaxf(rintf(h[j]*sc), -128.f), 127.f);
  *(int2*)(outq + (long)row*DIMC + tid*8) = o;
  if (tid == 0) rowdeq[row] = 1.0f / sc;
}

// ---------------- RoPE (cols [0,2560)) + V transpose, one dispatch ----------------
__global__ __launch_bounds__(256) void k_ropevt(u16* __restrict__ y,
                                                const int* __restrict__ pos_ids,
                                                u16* __restrict__ VT){
  if (blockIdx.x < 20480){
    int idx = blockIdx.x*256 + threadIdx.x;     // < 4096*1280
    int m = idx / 1280;
    int p = idx - m*1280;
    int c = p*2;
    int i = (c & 127) >> 1;
    float pos = (float)pos_ids[m];
    float inv = expf((float)i * -0.14391156831212787f);  // 10000^(-i/64)
    float f = pos * inv;
    float sn, cs;
    sincosf(f, &sn, &cs);
    u32* pr = (u32*)(y + (long)m*QKV_N + c);
    u32 both = *pr;
    float x0 = bf2f((u16)(both & 0xffffu));
    float x1 = bf2f((u16)(both >> 16));
    u16 o0 = f2bf(x0*cs - x1*sn);
    u16 o1 = f2bf(x1*cs + x0*sn);
    *pr = (u32)o0 | ((u32)o1 << 16);
  } else {
    int idx = (blockIdx.x - 20480)*256 + threadIdx.x;
    int d  = idx & 127;
    int hk = (idx >> 7) & 3;
    int b  = (idx >> 9) & 1;
    int tg = idx >> 10;                       // 0..255
    int tok0 = tg*8;
    const u16* src = y + ((long)b*SEQ + tok0)*QKV_N + 2560 + hk*128 + d;
    u16 tmp[8];
#pragma unroll
    for (int e = 0; e < 8; e++) tmp[e] = src[(long)e*QKV_N];
    *(int4*)(VT + (((long)(b*4+hk))*128 + d)*SEQ + tok0) = *(int4*)tmp;
  }
}

// ---------------- GEMM (i8 MFMA, in-place pipelined staging) ----------------
// MODE 0: QKV  -> bf16 out + bias, deq by section {q,k,v}, ldc=3072
// MODE 1: fp32 out = acc*rd*deq + resid, ldc=N       (O-proj and Down)
// MODE 2: GU   -> bf16 out, deq by half {gate,up}, ldc=11008
template<int MODE>
__global__ __launch_bounds__(256) void k_gemm(
    const char* __restrict__ A, const char* __restrict__ B,
    int K, int lda, int ldb, int ldc,
    const float* __restrict__ rowdeq, const float* __restrict__ deqp,
    const float* __restrict__ bq, const float* __restrict__ bk, const float* __restrict__ bv,
    const float* __restrict__ resid, float* __restrict__ outF, u16* __restrict__ outB)
{
  __shared__ char sA[128*64];
  __shared__ char sB[128*64];
  const int tid = threadIdx.x;
  const int lane = tid & 63, wv = tid >> 6;
  const int wr = wv >> 1, wc = wv & 1;
  const long m0 = (long)blockIdx.y * 128;
  const long n0 = (long)blockIdx.x * 128;
  const int r = lane & 15, qq = lane >> 4;

  i32x4 acc[4][4];
#pragma unroll
  for (int i = 0; i < 4; i++)
#pragma unroll
    for (int j = 0; j < 4; j++) acc[i][j] = (i32x4){0,0,0,0};

  const int c0 = tid, c1 = tid + 256;
  const char* gA0 = A + (m0 + (c0>>2))*lda + (c0&3)*16;
  const char* gA1 = A + (m0 + (c1>>2))*lda + (c1&3)*16;
  const char* gB0 = B + (n0 + (c0>>2))*ldb + (c0&3)*16;
  const char* gB1 = B + (n0 + (c1>>2))*ldb + (c1&3)*16;
  char* lA0 = sA + c0*16; char* lA1 = sA + c1*16;
  char* lB0 = sB + c0*16; char* lB1 = sB + c1*16;

  // preload tile 0
  GLD16(gA0, lA0);
  GLD16(gA1, lA1);
  GLD16(gB0, lB0);
  GLD16(gB1, lB1);
  __syncthreads();

  for (int kt = 0; kt < K; kt += 64){
    // LDS -> regs
    i32x4 aF[4], bF[4];
#pragma unroll
    for (int i = 0; i < 4; i++) aF[i] = *(const i32x4*)(sA + (wr*64 + 16*i + r)*64 + qq*16);
#pragma unroll
    for (int j = 0; j < 4; j++) bF[j] = *(const i32x4*)(sB + (wc*64 + 16*j + r)*64 + qq*16);
    __syncthreads();                 // everyone done reading LDS (lgkm drained)
    if (kt + 64 < K){                // issue next tile; flies during MFMA
      GLD16(gA0 + kt + 64, lA0);
      GLD16(gA1 + kt + 64, lA1);
      GLD16(gB0 + kt + 64, lB0);
      GLD16(gB1 + kt + 64, lB1);
    }
#pragma unroll
    for (int i = 0; i < 4; i++)
#pragma unroll
      for (int j = 0; j < 4; j++)
        acc[i][j] = __builtin_amdgcn_mfma_i32_16x16x64_i8(aF[i], bF[j], acc[i][j], 0, 0, 0);
    __syncthreads();                 // drains next-tile loads (vmcnt before barrier)
  }

#pragma unroll
  for (int i = 0; i < 4; i++){
#pragma unroll
    for (int t = 0; t < 4; t++){
      const long row = m0 + wr*64 + 16*i + 4*qq + t;
      const float rdv = rowdeq[row];
#pragma unroll
      for (int j = 0; j < 4; j++){
        const long col = n0 + wc*64 + 16*j + r;
        float vv = (float)acc[i][j][t];
        if (MODE == 0){
          int sec = (col >= 2048) + (col >= 2560);
          float dq = deqp[sec];
          float bias = (sec == 0) ? bq[col] : (sec == 1) ? bk[col-2048] : bv[col-2560];
          outB[row*(long)ldc + col] = f2bf(vv*rdv*dq + bias);
        } else if (MODE == 1){
          outF[row*(long)ldc + col] = vv*rdv*deqp[0] + resid[row*(long)ldc + col];
        } else {
          int sec = (col >= 5504) ? 1 : 0;
          outB[row*(long)ldc + col] = f2bf(vv*rdv*deqp[sec]);
        }
      }
    }
  }
}

// ---------------- flash attention v4: in-place pipelined, swizzled LDS ----------------
// Block p handles q-tiles (31-p) then (p): 33 tile-iters for every block.
// K/V staged via async global_load_lds into XOR-swizzled unpadded tiles; Q read
// directly from global into A-fragments. K(i+1) issued after S (flies through
// softmax+PV); V(i+1) issued after PV (flies through next S).
__global__ __launch_bounds__(256) void k_attn(const u16* __restrict__ Y,
                                              const u16* __restrict__ VT,
                                              float* __restrict__ O)
{
  __shared__ u16 Ks[64*128];     // [key][d], 16B group g stored at g^(key&7)
  __shared__ u16 VTs[128*64];    // [d][key], 16B group g stored at g^(d&7)
  __shared__ u16 Ps[64][72];     // P tile (wave-private rows, padded)

  const int pp = blockIdx.x;               // 0..15
  const int bh = blockIdx.y;
  const int b = bh >> 4, h = bh & 15, hk = h >> 2;
  const int tid = threadIdx.x;
  const int lane = tid & 63, wv = tid >> 6;
  const int r = lane & 15, qq = lane >> 4;
  const long rowbase = (long)b * SEQ;
  const u16* Kbase = Y + rowbase*QKV_N + 2048 + hk*128;
  const u16* Vbase = VT + ((long)(b*4+hk))*128*SEQ;

  for (int ph = 0; ph < 2; ph++){
    const int qt = ph ? pp : 31 - pp;
    const int q0 = qt * 64;

    // Q A-fragments: 16B-contiguous in global, load direct (no LDS)
    bf16x8 qf[4];
#pragma unroll
    for (int kc = 0; kc < 4; kc++)
      qf[kc] = *(const bf16x8*)(Y + (rowbase + q0 + wv*16 + r)*QKV_N + h*128 + kc*32 + qq*8);

    // preload tile 0
#pragma unroll
    for (int rnd = 0; rnd < 4; rnd++){
      int c = rnd*256 + tid;
      int row = c >> 4, g = (c & 15) ^ (row & 7);
      GLD16(Kbase + ((long)(qt*0 + row))*QKV_N + g*8, (char*)Ks + c*16);
    }
#pragma unroll
    for (int rnd = 0; rnd < 4; rnd++){
      int c = rnd*256 + tid;
      int d = c >> 3, g = (c & 7) ^ (d & 7);
      GLD16(Vbase + (long)d*SEQ + g*8, (char*)VTs + c*16);
    }
    __syncthreads();

    f32x4 accO[8];
#pragma unroll
    for (int jn = 0; jn < 8; jn++) accO[jn] = (f32x4){0.f,0.f,0.f,0.f};
    float m_run[4] = {-INFINITY,-INFINITY,-INFINITY,-INFINITY};
    float l_run[4] = {0.f,0.f,0.f,0.f};

    for (int kt = 0; kt <= qt; kt++){
      // S = Q K^T
      float sv[4][4];
#pragma unroll
      for (int j = 0; j < 4; j++){
        f32x4 a = (f32x4){0.f,0.f,0.f,0.f};
#pragma unroll
        for (int kc = 0; kc < 4; kc++){
          bf16x8 kf = *(const bf16x8*)(Ks + (16*j + r)*128 + (((kc*4 + qq) ^ (r & 7)))*8);
          a = __builtin_amdgcn_mfma_f32_16x16x32_bf16(qf[kc], kf, a, 0, 0, 0);
        }
#pragma unroll
        for (int t = 0; t < 4; t++) sv[j][t] = a[t] * ATT_SCALE;
      }
      __syncthreads();                       // bar1: Ks free; drains V(kt) of prev iter
      if (kt < qt){                          // issue K(kt+1); flies during softmax+PV
#pragma unroll
        for (int rnd = 0; rnd < 4; rnd++){
          int c = rnd*256 + tid;
          int row = c >> 4, g = (c & 15) ^ (row & 7);
          GLD16(Kbase + ((long)((kt+1)*64 + row))*QKV_N + g*8, (char*)Ks + c*16);
        }
      }
      if (kt == qt){
#pragma unroll
        for (int j = 0; j < 4; j++){
          int key = kt*64 + 16*j + r;
#pragma unroll
          for (int t = 0; t < 4; t++){
            int qr = q0 + wv*16 + 4*qq + t;
            if (key > qr) sv[j][t] = -INFINITY;
          }
        }
      }
      // online softmax per q-row (wave-private rows)
#pragma unroll
      for (int t = 0; t < 4; t++){
        float mm = fmaxf(fmaxf(sv[0][t],sv[1][t]), fmaxf(sv[2][t],sv[3][t]));
#pragma unroll
        for (int o = 8; o > 0; o >>= 1) mm = fmaxf(mm, __shfl_xor(mm, o));
        float mnew = fmaxf(m_run[t], mm);
        float alpha = __expf(m_run[t] - mnew);
        m_run[t] = mnew;
        float ps = 0.f;
#pragma unroll
        for (int j = 0; j < 4; j++){
          float p = __expf(sv[j][t] - mnew);
          ps += p;
          Ps[wv*16 + 4*qq + t][16*j + r] = f2bf(p);
        }
#pragma unroll
        for (int o = 8; o > 0; o >>= 1) ps += __shfl_xor(ps, o);
        l_run[t] = l_run[t]*alpha + ps;
#pragma unroll
        for (int jn = 0; jn < 8; jn++) accO[jn][t] *= alpha;
      }
      // O += P V
#pragma unroll
      for (int kc = 0; kc < 2; kc++){
        bf16x8 pf = *(const bf16x8*)&Ps[wv*16 + r][kc*32 + qq*8];
#pragma unroll
        for (int jn = 0; jn < 8; jn++){
          bf16x8 vf = *(const bf16x8*)(VTs + (16*jn + r)*64 + (((kc*4 + qq) ^ (r & 7)))*8);
          accO[jn] = __builtin_amdgcn_mfma_f32_16x16x32_bf16(pf, vf, accO[jn], 0, 0, 0);
        }
      }
      __syncthreads();                       // bar2: VTs free; drains K(kt+1)
      if (kt < qt){                          // issue V(kt+1); flies during next S
#pragma unroll
        for (int rnd = 0; rnd < 4; rnd++){
          int c = rnd*256 + tid;
          int d = c >> 3, g = (c & 7) ^ (d & 7);
          GLD16(Vbase + (long)d*SEQ + (kt+1)*64 + g*8, (char*)VTs + c*16);
        }
      }
    }
    float inv[4];
#pragma unroll
    for (int t = 0; t < 4; t++) inv[t] = 1.0f / l_run[t];
#pragma unroll
    for (int jn = 0; jn < 8; jn++){
#pragma unroll
      for (int t = 0; t < 4; t++){
        long row = rowbase + q0 + wv*16 + 4*qq + t;
        O[row*DIMC + h*128 + 16*jn + r] = accO[jn][t]*inv[t];
      }
    }
    __syncthreads();   // protect Ks/VTs before next phase preload
  }
}

// ---------------- SwiGLU + act_quant: ygu bf16 -> i8 [4096][5504] ----------------
__global__ __launch_bounds__(256) void k_swiglu(const u16* __restrict__ ygu,
                                                char* __restrict__ qout,
                                                float* __restrict__ rowdeq){
  const int row = blockIdx.x, tid = threadIdx.x;
  const u16* base = ygu + (long)row * GU_N;
  float h[24];
  float amax = 0.f;
#pragma unroll
  for (int it = 0; it < 3; it++){
    int chunk = it*256 + tid;
    if (chunk < 688){
      int j0 = chunk*8;
      int4 g4 = *(const int4*)(base + j0);
      int4 u4 = *(const int4*)(base + MLP_P + j0);
      const u16* gp = (const u16*)&g4;
      const u16* up = (const u16*)&u4;
#pragma unroll
      for (int e = 0; e < 8; e++){
        float g = bf2f(gp[e]);
        float u = bf2f(up[e]);
        float hv = g * (1.0f/(1.0f + __expf(-g))) * u;
        h[it*8+e] = hv;
        amax = fmaxf(amax, fabsf(hv));
      }
    } else {
#pragma unroll
      for (int e = 0; e < 8; e++) h[it*8+e] = 0.f;
    }
  }
  amax = waveRedMax(amax);
  __shared__ float sm[4];
  int lane = tid & 63, wv = tid >> 6;
  if (lane == 0) sm[wv] = amax;
  __syncthreads();
  float gmax = fmaxf(fmaxf(sm[0],sm[1]), fmaxf(sm[2],sm[3]));
  float sc = 127.0f / fmaxf(gmax, 1e-5f);
#pragma unroll
  for (int it = 0; it < 3; it++){
    int chunk = it*256 + tid;
    if (chunk < 688){
      int j0 = chunk*8;
      int2 o;
      char* oc = (char*)&o;
#pragma unroll
      for (int e = 0; e < 8; e++)
        oc[e] = (char)(int)fminf(fmaxf(rintf(h[it*8+e]*sc), -128.f), 127.f);
      *(int2*)(qout + (long)row*MLP_P + j0) = o;
    }
  }
  if (tid == 0) rowdeq[row] = 1.0f/sc;
}

extern "C" void kernel_launch(void* const* d_in, const int* in_sizes, int n_in,
                              void* d_out, int out_size, void* d_ws, size_t ws_size,
                              hipStream_t stream)
{
  (void)in_sizes; (void)n_in; (void)out_size; (void)ws_size;
  const float* x   = (const float*)d_in[0];
  const int*   pos = (const int*)d_in[1];
  const float* n1w = (const float*)d_in[2];
  const float* qw  = (const float*)d_in[3];
  const float* qb  = (const float*)d_in[4];
  const float* kw  = (const float*)d_in[5];
  const float* kb  = (const float*)d_in[6];
  const float* vw  = (const float*)d_in[7];
  const float* vb  = (const float*)d_in[8];
  const float* ow  = (const float*)d_in[9];
  const float* n2w = (const float*)d_in[10];
  const float* gw  = (const float*)d_in[11];
  const float* uw  = (const float*)d_in[12];
  const float* dw  = (const float*)d_in[13];
  float* out = (float*)d_out;
  char* ws = (char*)d_ws;

  // workspace layout (all offsets multiple of 256)
  float* sc   = (float*)ws;                 // [0..6] sums, [8..14] deq
  char* Wqkv  = ws + 256;                   // [3072][2048] i8   (6.29 MB)
  char* Wo    = ws + 6291712;               // [2048][2048] i8   (4.19 MB)
  char* Wgu   = ws + 10486016;              // [11008][2048] i8  (22.5 MB)
  char* Wd    = ws + 33030400;              // [2048][5504] i8   (11.3 MB)
  char* actq  = ws + 44302592;              // [4096][2048] i8   (8.39 MB)
  char* swq   = ws + 52691200;              // [4096][5504] i8   (22.5 MB)
  float* rd   = (float*)(ws + 75235584);    // [4096] fp32
  char* xreg  = ws + 75252224;              // overlay region (90.2 MB)
  u16* yqkv   = (u16*)xreg;                 // [4096][3072] bf16 (25.2 MB)
  float* attn = (float*)(xreg + 25165824);  // [4096][2048] fp32 (33.6 MB)
  u16* vT     = (u16*)(xreg + 58720256);    // [8][128][2048] bf16 (8.4 MB)
  u16* ygu    = (u16*)xreg;                 // [4096][11008] bf16 (90.2 MB, after attention)

  // ---- weight scales + ternary i8 quant (fused dispatches) ----
  hipMemsetAsync(sc, 0, 64, stream);
  k_abssum7<<<dim3(512,7),256,0,stream>>>((const float4*)qw, (const float4*)kw,
                                          (const float4*)vw, (const float4*)ow,
                                          (const float4*)gw, (const float4*)uw,
                                          (const float4*)dw, sc);
  k_finalize<<<1,64,0,stream>>>(sc);
  k_wquant6<<<dim3(512,6),256,0,stream>>>((const float4*)qw, (const float4*)kw,
                                          (const float4*)vw, (const float4*)ow,
                                          (const float4*)gw, (const float4*)uw,
                                          (u32*)Wqkv, (u32*)(Wqkv + 2048l*2048),
                                          (u32*)(Wqkv + 2560l*2048), (u32*)Wo,
                                          (u32*)Wgu, (u32*)(Wgu + 5504l*2048), sc);
  hipMemsetAsync(Wgu + 5461l*2048,        0, 43l*2048, stream);
  hipMemsetAsync(Wgu + (5504l+5461)*2048, 0, 43l*2048, stream);
  k_wquant_down<<<11008,256,0,stream>>>(dw, (u32*)Wd, sc+14);

  // ---- attention half ----
  k_rmsq<<<4096,256,0,stream>>>(x, n1w, actq, rd, 1);
  k_gemm<0><<<dim3(24,32),256,0,stream>>>(actq, Wqkv, 2048, 2048, 2048, 3072,
                                          rd, sc+8, qb, kb, vb, nullptr, nullptr, yqkv);
  k_ropevt<<<21504,256,0,stream>>>(yqkv, pos, vT);
  k_attn<<<dim3(16,32),256,0,stream>>>(yqkv, vT, attn);
  k_rmsq<<<4096,256,0,stream>>>(attn, n1w, actq, rd, 0);
  k_gemm<1><<<dim3(16,32),256,0,stream>>>(actq, Wo, 2048, 2048, 2048, 2048,
                                          rd, sc+11, nullptr, nullptr, nullptr, x, out, nullptr);

  // ---- MLP half (x1 lives in d_out) ----
  k_rmsq<<<4096,256,0,stream>>>(out, n2w, actq, rd, 1);
  k_gemm<2><<<dim3(86,32),256,0,stream>>>(actq, Wgu, 2048, 2048, 2048, 11008,
                                          rd, sc+12, nullptr, nullptr, nullptr, nullptr, nullptr, ygu);
  k_swiglu<<<4096,256,0,stream>>>(ygu, swq, rd);
  k_gemm<1><<<dim3(16,32),256,0,stream>>>(swq, Wd, 5504, 5504, 5504, 2048,
                                          rd, sc+14, nullptr, nullptr, nullptr, out, out, nullptr);
}